// Round 3
// baseline (2542.232 us; speedup 1.0000x reference)
//
#include <hip/hip_runtime.h>
#include <cstdint>
#include <cstddef>

// ---- problem constants ----
#define NB 2
#define TSEQ 2048
#define HIDD 2048
#define NH 8
#define DKD 256
#define DVD 512
#define CHK 64
#define NCH 32
#define HDKD 2048
#define HDVD 4096

typedef __attribute__((ext_vector_type(8))) short s16x8;  // 8 bf16 (4 VGPRs)
typedef __attribute__((ext_vector_type(4))) float fx4;    // MFMA accum

__device__ __forceinline__ float bf2f(unsigned short u) {
  union { float f; uint32_t i; } x; x.i = ((uint32_t)u) << 16; return x.f;
}
__device__ __forceinline__ unsigned short f2bf(float f) {
  union { float f; uint32_t i; } x; x.f = f;
  uint32_t r = (x.i + 0x7fffu + ((x.i >> 16) & 1u)) >> 16;
  return (unsigned short)r;
}

// ================= elementwise f32 -> bf16 cast =================
__global__ __launch_bounds__(256) void cast_f32_bf16(const float* __restrict__ in,
                                                     unsigned short* __restrict__ out, int n8) {
  int idx = blockIdx.x * 256 + threadIdx.x;
  if (idx >= n8) return;
  const float4* p = (const float4*)(in + (size_t)idx * 8);
  float4 a = p[0], b = p[1];
  unsigned short u[8];
  u[0]=f2bf(a.x); u[1]=f2bf(a.y); u[2]=f2bf(a.z); u[3]=f2bf(a.w);
  u[4]=f2bf(b.x); u[5]=f2bf(b.y); u[6]=f2bf(b.z); u[7]=f2bf(b.w);
  *(uint4*)(out + (size_t)idx * 8) = *(uint4*)u;
}

// ================= transpose + cast: in[R][C] f32 -> out[C][R] bf16 =================
__global__ __launch_bounds__(256) void transpose_cast(const float* __restrict__ in,
                                                      unsigned short* __restrict__ out,
                                                      int R, int C) {
  __shared__ float tile[64][65];
  const int tid = threadIdx.x;
  const int c0 = blockIdx.x * 64, r0 = blockIdx.y * 64;
  #pragma unroll
  for (int it = 0; it < 4; ++it) {
    int idx = tid + it * 256;
    int row = idx >> 4, c4 = (idx & 15) * 4;
    float4 v = *(const float4*)(in + (size_t)(r0 + row) * C + c0 + c4);
    tile[row][c4 + 0] = v.x; tile[row][c4 + 1] = v.y;
    tile[row][c4 + 2] = v.z; tile[row][c4 + 3] = v.w;
  }
  __syncthreads();
  #pragma unroll
  for (int it = 0; it < 4; ++it) {
    int idx = tid + it * 256;
    int orow = idx >> 4, r4 = (idx & 15) * 4;
    ushort4 u;
    u.x = f2bf(tile[r4 + 0][orow]);
    u.y = f2bf(tile[r4 + 1][orow]);
    u.z = f2bf(tile[r4 + 2][orow]);
    u.w = f2bf(tile[r4 + 3][orow]);
    *(ushort4*)(out + (size_t)(c0 + orow) * R + r0 + r4) = u;
  }
}

// ================= gk projection: log_sigmoid(x @ Wgk + bgk)/16, all fp32 =================
__global__ __launch_bounds__(256) void gk_proj(const float* __restrict__ x,
                                               const float* __restrict__ Wgk,
                                               const float* __restrict__ bgk,
                                               float* __restrict__ gk) {
  const int row = blockIdx.x, tid = threadIdx.x;
  const float* xr = x + (size_t)row * HIDD;
  float acc[8];
  #pragma unroll
  for (int h = 0; h < 8; ++h) acc[h] = 0.f;
  for (int i = tid; i < HIDD; i += 256) {
    float xv = xr[i];
    const float4* wr = (const float4*)(Wgk + (size_t)i * 8);
    float4 w0 = wr[0], w1 = wr[1];
    acc[0] += xv * w0.x; acc[1] += xv * w0.y; acc[2] += xv * w0.z; acc[3] += xv * w0.w;
    acc[4] += xv * w1.x; acc[5] += xv * w1.y; acc[6] += xv * w1.z; acc[7] += xv * w1.w;
  }
  #pragma unroll
  for (int off = 32; off; off >>= 1) {
    #pragma unroll
    for (int h = 0; h < 8; ++h) acc[h] += __shfl_xor(acc[h], off, 64);
  }
  __shared__ float red[4][8];
  if ((tid & 63) == 0) {
    #pragma unroll
    for (int h = 0; h < 8; ++h) red[tid >> 6][h] = acc[h];
  }
  __syncthreads();
  if (tid < 8) {
    float z = red[0][tid] + red[1][tid] + red[2][tid] + red[3][tid] + bgk[tid];
    float ls = fminf(z, 0.f) - log1pf(__expf(-fabsf(z)));
    gk[(size_t)row * 8 + tid] = ls * (1.0f / 16.0f);
  }
}

// ================= bf16 GEMM: C[M][N] = A[M][K] * BT[N][K]^T =================
// 128x128 tile, BK=64, 4 waves (2x2 of 64x64), 16x16x32 MFMA, XOR-swizzled LDS,
// reg-staged with next-tile prefetch issued after the barrier (overlaps MFMA).
template<int OUT_BF16>
__global__ __launch_bounds__(256, 2) void gemm_bt(const unsigned short* __restrict__ A,
                                                  const unsigned short* __restrict__ BT,
                                                  void* __restrict__ C,
                                                  int M, int N, int K) {
  __shared__ uint4 As4[1024];
  __shared__ uint4 Bs4[1024];
  const int tid = threadIdx.x, l = tid & 63;
  const int l15 = l & 15, l4 = l >> 4;
  const int w = tid >> 6, wm = w >> 1, wn = w & 1;
  const int m0 = blockIdx.y * 128, n0 = blockIdx.x * 128;
  const int nk = K >> 6;

  fx4 zero = {0.f, 0.f, 0.f, 0.f};
  fx4 acc[4][4];
  #pragma unroll
  for (int mi = 0; mi < 4; ++mi)
    #pragma unroll
    for (int ni = 0; ni < 4; ++ni) acc[mi][ni] = zero;

  uint4 ra[4], rb[4];
  #pragma unroll
  for (int i = 0; i < 4; ++i) {
    int idx = tid + i * 256, row = idx >> 3, c8 = idx & 7;
    ra[i] = *(const uint4*)(A  + (size_t)(m0 + row) * K + c8 * 8);
    rb[i] = *(const uint4*)(BT + (size_t)(n0 + row) * K + c8 * 8);
  }
  for (int kt = 0; kt < nk; ++kt) {
    __syncthreads();
    #pragma unroll
    for (int i = 0; i < 4; ++i) {
      int idx = tid + i * 256, row = idx >> 3, c8 = idx & 7;
      As4[row * 8 + (c8 ^ (row & 7))] = ra[i];
      Bs4[row * 8 + (c8 ^ (row & 7))] = rb[i];
    }
    __syncthreads();
    if (kt + 1 < nk) {
      #pragma unroll
      for (int i = 0; i < 4; ++i) {
        int idx = tid + i * 256, row = idx >> 3, c8 = idx & 7;
        ra[i] = *(const uint4*)(A  + (size_t)(m0 + row) * K + (kt + 1) * 64 + c8 * 8);
        rb[i] = *(const uint4*)(BT + (size_t)(n0 + row) * K + (kt + 1) * 64 + c8 * 8);
      }
    }
    const unsigned short* Ap = (const unsigned short*)As4;
    const unsigned short* Bp = (const unsigned short*)Bs4;
    #pragma unroll
    for (int ks = 0; ks < 2; ++ks) {
      s16x8 af[4], bf[4];
      #pragma unroll
      for (int i = 0; i < 4; ++i) {
        int arow = wm * 64 + i * 16 + l15;
        af[i] = *(const s16x8*)(Ap + arow * 64 + (((ks * 4 + l4) ^ (arow & 7)) << 3));
        int brow = wn * 64 + i * 16 + l15;
        bf[i] = *(const s16x8*)(Bp + brow * 64 + (((ks * 4 + l4) ^ (brow & 7)) << 3));
      }
      #pragma unroll
      for (int mi = 0; mi < 4; ++mi)
        #pragma unroll
        for (int ni = 0; ni < 4; ++ni)
          acc[mi][ni] = __builtin_amdgcn_mfma_f32_16x16x32_bf16(af[mi], bf[ni], acc[mi][ni], 0, 0, 0);
    }
  }
  #pragma unroll
  for (int mi = 0; mi < 4; ++mi) {
    #pragma unroll
    for (int r = 0; r < 4; ++r) {
      const size_t row = m0 + wm * 64 + mi * 16 + l4 * 4 + r;
      #pragma unroll
      for (int ni = 0; ni < 4; ++ni) {
        const int col = n0 + wn * 64 + ni * 16 + l15;
        if (OUT_BF16) ((unsigned short*)C)[row * N + col] = f2bf(acc[mi][ni][r]);
        else          ((float*)C)[row * N + col] = acc[mi][ni][r];
      }
    }
  }
}

// ================= chunked GLA scan =================
// grid = B*H*(DV/64) = 128 blocks; 4 waves; wave w owns dv slice [w*16, w*16+16).
// S[256][64] fp32 lives in MFMA accumulators (16 frags/lane).
__global__ __launch_bounds__(256, 1) void gla_kernel(const unsigned short* __restrict__ qb,
                                                     const unsigned short* __restrict__ kb,
                                                     const unsigned short* __restrict__ vb,
                                                     const float* __restrict__ gkw,
                                                     unsigned short* __restrict__ oat) {
  const int blk = blockIdx.x;
  const int dvb = blk & 7, h = (blk >> 3) & 7, b = blk >> 6;
  const int dv0 = dvb * 64;
  const int tid = threadIdx.x, l = tid & 63, w = tid >> 6;
  const int l15 = l & 15, l4 = l >> 4;

  __shared__ __align__(16) unsigned short stkt[64 * 256];  // ST [64dv][256dk] / kT [256dk][64cc]
  __shared__ __align__(16) unsigned short vTs[64 * 64];    // vT [64dv][64cc]
  __shared__ __align__(16) unsigned short Als[64 * 64];    // A  [64c][64cc]
  __shared__ float gis[64];

  fx4 zero = {0.f, 0.f, 0.f, 0.f};
  fx4 S[16];
  #pragma unroll
  for (int t = 0; t < 16; ++t) S[t] = zero;

  const unsigned short* qbase = qb + (size_t)b * TSEQ * HDKD + h * DKD;
  const unsigned short* kbase = kb + (size_t)b * TSEQ * HDKD + h * DKD;
  const unsigned short* vbase = vb + (size_t)b * TSEQ * HDVD + h * DVD + dv0;
  const float*  gbase = gkw + (size_t)b * TSEQ * NH + h;
  unsigned short* obase = oat + (size_t)b * TSEQ * HDVD + h * DVD + dv0;

  const float scale = 0.0625f;  // DK^-0.5

  for (int c = 0; c < NCH; ++c) {
    const int t0 = c * CHK;
    // ---- phase 0: gi cumsum, S -> ST(bf16) LDS, stage vT ----
    if (tid < 64) {
      float xg = gbase[(size_t)(t0 + tid) * NH];
      #pragma unroll
      for (int off = 1; off < 64; off <<= 1) {
        float y = __shfl_up(xg, off, 64);
        if (l >= off) xg += y;
      }
      gis[tid] = xg;
    }
    {
      const int dvl = w * 16 + l15;
      #pragma unroll
      for (int t = 0; t < 16; ++t) {
        const int dk0 = t * 16 + l4 * 4;
        ushort4 p;
        p.x = f2bf(S[t].x); p.y = f2bf(S[t].y); p.z = f2bf(S[t].z); p.w = f2bf(S[t].w);
        *(ushort4*)((char*)stkt + dvl * 512 + (((dk0 >> 3) ^ (dvl & 7)) << 4) + (dk0 & 7) * 2) = p;
      }
    }
    #pragma unroll
    for (int it = 0; it < 2; ++it) {
      const int idx = tid + it * 256;
      const int cc = idx >> 3, c8 = idx & 7;
      uint4 vv = *(const uint4*)(vbase + (size_t)(t0 + cc) * HDVD + c8 * 8);
      const unsigned short* u = (const unsigned short*)&vv;
      #pragma unroll
      for (int j = 0; j < 8; ++j) {
        const int dv = c8 * 8 + j;
        vTs[dv * 64 + (((cc >> 3) ^ (dv & 7)) << 3) + (cc & 7)] = u[j];
      }
    }
    __syncthreads();

    // ---- phase 1: O1 = q @ S  and  Araw = q @ k^T (k-frags direct from global) ----
    s16x8 kf[8], stf[8];
    {
      const unsigned short* krow = kbase + (size_t)(t0 + w * 16 + l15) * HDKD;
      const int dvl = w * 16 + l15;
      #pragma unroll
      for (int ks = 0; ks < 8; ++ks) {
        kf[ks] = *(const s16x8*)(krow + ks * 32 + l4 * 8);
        const int chunk = (ks * 4 + l4) ^ (dvl & 7);
        stf[ks] = *(const s16x8*)(stkt + dvl * 256 + chunk * 8);
      }
    }
    fx4 o1[4], ar[4];
    #pragma unroll
    for (int ct = 0; ct < 4; ++ct) {
      o1[ct] = zero; ar[ct] = zero;
      const unsigned short* qrow = qbase + (size_t)(t0 + ct * 16 + l15) * HDKD;
      #pragma unroll
      for (int ks = 0; ks < 8; ++ks) {
        s16x8 qf = *(const s16x8*)(qrow + ks * 32 + l4 * 8);
        o1[ct] = __builtin_amdgcn_mfma_f32_16x16x32_bf16(qf, stf[ks], o1[ct], 0, 0, 0);
        ar[ct] = __builtin_amdgcn_mfma_f32_16x16x32_bf16(qf, kf[ks], ar[ct], 0, 0, 0);
      }
    }
    // mask + decay A -> LDS (bf16); scale O1 rows by scale*exp(gi)
    {
      const int j = w * 16 + l15;
      const float gj = gis[j];
      #pragma unroll
      for (int ct = 0; ct < 4; ++ct) {
        #pragma unroll
        for (int r = 0; r < 4; ++r) {
          const int i = ct * 16 + l4 * 4 + r;
          const float gi = gis[i];
          float av = (i >= j) ? ar[ct][r] * scale * __expf(gi - gj) : 0.f;
          Als[i * 64 + (((j >> 3) ^ (i & 7)) << 3) + (j & 7)] = f2bf(av);
          o1[ct][r] *= scale * __expf(gi);
        }
      }
    }
    __syncthreads();

    // ---- phase 2: build kT' = (k * exp(gl - gi))^T into stkt ----
    #pragma unroll
    for (int it = 0; it < 8; ++it) {
      const int idx = tid + it * 256;
      const int cc = idx >> 5, c32 = idx & 31;
      uint4 kv = *(const uint4*)(kbase + (size_t)(t0 + cc) * HDKD + c32 * 8);
      const unsigned short* u = (const unsigned short*)&kv;
      const float e = __expf(gis[63] - gis[cc]);
      #pragma unroll
      for (int j = 0; j < 8; ++j) {
        const int dk = c32 * 8 + j;
        stkt[dk * 64 + (((cc >> 3) ^ (dk & 7)) << 3) + (cc & 7)] = f2bf(bf2f(u[j]) * e);
      }
    }
    __syncthreads();

    // ---- phase 3: o = O1 + A@v (write out); S = exp(gl)*S + kT' @ v ----
    s16x8 vf[2];
    {
      const int dv = w * 16 + l15;
      #pragma unroll
      for (int ks = 0; ks < 2; ++ks) {
        const int chunk = (ks * 4 + l4) ^ (dv & 7);
        vf[ks] = *(const s16x8*)(vTs + dv * 64 + chunk * 8);
      }
    }
    #pragma unroll
    for (int ct = 0; ct < 4; ++ct) {
      const int i = ct * 16 + l15;
      #pragma unroll
      for (int ks = 0; ks < 2; ++ks) {
        const int chunk = (ks * 4 + l4) ^ (i & 7);
        s16x8 af = *(const s16x8*)(Als + i * 64 + chunk * 8);
        o1[ct] = __builtin_amdgcn_mfma_f32_16x16x32_bf16(af, vf[ks], o1[ct], 0, 0, 0);
      }
      #pragma unroll
      for (int r = 0; r < 4; ++r) {
        const int tt = t0 + ct * 16 + l4 * 4 + r;
        obase[(size_t)tt * HDVD + w * 16 + l15] = f2bf(o1[ct][r]);
      }
    }
    {
      const float egl = __expf(gis[63]);
      #pragma unroll
      for (int t = 0; t < 16; ++t) {
        S[t].x *= egl; S[t].y *= egl; S[t].z *= egl; S[t].w *= egl;
        const int dk = t * 16 + l15;
        #pragma unroll
        for (int ks = 0; ks < 2; ++ks) {
          const int chunk = (ks * 4 + l4) ^ (dk & 7);
          s16x8 ktf = *(const s16x8*)(stkt + dk * 64 + chunk * 8);
          S[t] = __builtin_amdgcn_mfma_f32_16x16x32_bf16(ktf, vf[ks], S[t], 0, 0, 0);
        }
      }
    }
    __syncthreads();  // protect stkt/vTs/Als/gis before next chunk's phase 0
  }
}

// ================= fused RMSnorm * norm_w * silu(g), in-place on o =================
__global__ __launch_bounds__(256) void norm_gate(unsigned short* __restrict__ o,
                                                 const unsigned short* __restrict__ g,
                                                 const float* __restrict__ nw) {
  const int seg = blockIdx.x * 4 + (threadIdx.x >> 6);
  const int l = threadIdx.x & 63;
  const size_t base = (size_t)seg * 512 + l * 8;
  uint4 ov = *(const uint4*)(o + base);
  const unsigned short* ou = (const unsigned short*)&ov;
  float f[8], ss = 0.f;
  #pragma unroll
  for (int j = 0; j < 8; ++j) { f[j] = bf2f(ou[j]); ss += f[j] * f[j]; }
  #pragma unroll
  for (int off = 32; off; off >>= 1) ss += __shfl_xor(ss, off, 64);
  const float rms = rsqrtf(ss * (1.0f / 512.0f) + 1e-5f);
  uint4 gv = *(const uint4*)(g + base);
  const unsigned short* gu = (const unsigned short*)&gv;
  const float4 w0 = *(const float4*)(nw + l * 8);
  const float4 w1 = *(const float4*)(nw + l * 8 + 4);
  float wv[8] = {w0.x, w0.y, w0.z, w0.w, w1.x, w1.y, w1.z, w1.w};
  unsigned short ru[8];
  #pragma unroll
  for (int j = 0; j < 8; ++j) {
    float gf = bf2f(gu[j]);
    float si = gf / (1.f + __expf(-gf));
    ru[j] = f2bf(f[j] * rms * wv[j] * si);
  }
  *(uint4*)(o + base) = *(uint4*)ru;
}

// ================= launch =================
extern "C" void kernel_launch(void* const* d_in, const int* in_sizes, int n_in,
                              void* d_out, int out_size, void* d_ws, size_t ws_size,
                              hipStream_t stream) {
  (void)in_sizes; (void)n_in; (void)out_size; (void)ws_size;
  const float* x   = (const float*)d_in[0];
  const float* Wq  = (const float*)d_in[1];
  const float* Wk  = (const float*)d_in[2];
  const float* Wv  = (const float*)d_in[3];
  const float* Wg  = (const float*)d_in[4];
  const float* Wgk = (const float*)d_in[5];
  const float* bgk = (const float*)d_in[6];
  const float* Wo  = (const float*)d_in[7];
  const float* nw  = (const float*)d_in[8];

  char* ws = (char*)d_ws;
  size_t off = 0;
  auto alloc = [&](size_t bytes) -> void* {
    void* p = ws + off; off += (bytes + 255) & ~(size_t)255; return p;
  };
  unsigned short* xb  = (unsigned short*)alloc((size_t)4096 * 2048 * 2);
  unsigned short* wqT = (unsigned short*)alloc((size_t)2048 * 2048 * 2);
  unsigned short* wkT = (unsigned short*)alloc((size_t)2048 * 2048 * 2);
  unsigned short* wvT = (unsigned short*)alloc((size_t)4096 * 2048 * 2);
  unsigned short* wgT = (unsigned short*)alloc((size_t)4096 * 2048 * 2);
  unsigned short* woT = (unsigned short*)alloc((size_t)2048 * 4096 * 2);
  unsigned short* qb  = (unsigned short*)alloc((size_t)4096 * 2048 * 2);
  unsigned short* kb  = (unsigned short*)alloc((size_t)4096 * 2048 * 2);
  unsigned short* vb  = (unsigned short*)alloc((size_t)4096 * 4096 * 2);
  unsigned short* gb  = (unsigned short*)alloc((size_t)4096 * 4096 * 2);
  unsigned short* oat = (unsigned short*)alloc((size_t)4096 * 4096 * 2);
  float* gkb          = (float*)alloc((size_t)4096 * 8 * 4);

  cast_f32_bf16<<<4096, 256, 0, stream>>>(x, xb, 4096 * 2048 / 8);
  transpose_cast<<<dim3(32, 32), 256, 0, stream>>>(Wq, wqT, 2048, 2048);
  transpose_cast<<<dim3(32, 32), 256, 0, stream>>>(Wk, wkT, 2048, 2048);
  transpose_cast<<<dim3(64, 32), 256, 0, stream>>>(Wv, wvT, 2048, 4096);
  transpose_cast<<<dim3(64, 32), 256, 0, stream>>>(Wg, wgT, 2048, 4096);
  transpose_cast<<<dim3(32, 64), 256, 0, stream>>>(Wo, woT, 4096, 2048);
  gk_proj<<<4096, 256, 0, stream>>>(x, Wgk, bgk, gkb);

  gemm_bt<1><<<dim3(16, 32), 256, 0, stream>>>(xb, wqT, qb, 4096, 2048, 2048);
  gemm_bt<1><<<dim3(16, 32), 256, 0, stream>>>(xb, wkT, kb, 4096, 2048, 2048);
  gemm_bt<1><<<dim3(32, 32), 256, 0, stream>>>(xb, wvT, vb, 4096, 4096, 2048);
  gemm_bt<1><<<dim3(32, 32), 256, 0, stream>>>(xb, wgT, gb, 4096, 4096, 2048);

  gla_kernel<<<128, 256, 0, stream>>>(qb, kb, vb, gkb, oat);
  norm_gate<<<8192, 256, 0, stream>>>(oat, gb, nw);

  gemm_bt<0><<<dim3(16, 32), 256, 0, stream>>>(oat, woT, d_out, 4096, 2048, 4096);
}

// Round 5
// 854.146 us; speedup vs baseline: 2.9763x; 2.9763x over previous
//
#include <hip/hip_runtime.h>
#include <cstdint>
#include <cstddef>

// ---- problem constants ----
#define NB 2
#define TSEQ 2048
#define HIDD 2048
#define NH 8
#define DKD 256
#define DVD 512
#define CHK 64
#define NCH 32
#define HDKD 2048
#define HDVD 4096

typedef __attribute__((ext_vector_type(8))) short s16x8;  // 8 bf16 (4 VGPRs)
typedef __attribute__((ext_vector_type(4))) float fx4;    // MFMA accum

__device__ __forceinline__ float bf2f(unsigned short u) {
  union { float f; uint32_t i; } x; x.i = ((uint32_t)u) << 16; return x.f;
}
__device__ __forceinline__ unsigned short f2bf(float f) {
  union { float f; uint32_t i; } x; x.f = f;
  uint32_t r = (x.i + 0x7fffu + ((x.i >> 16) & 1u)) >> 16;
  return (unsigned short)r;
}

// async global->LDS, 16B per lane; LDS dest = wave-uniform base + lane*16
__device__ __forceinline__ void gload16(const unsigned short* g, unsigned short* l) {
  __builtin_amdgcn_global_load_lds(
      (const __attribute__((address_space(1))) void*)g,
      (__attribute__((address_space(3))) void*)l, 16, 0, 0);
}

// ================= elementwise f32 -> bf16 cast =================
__global__ __launch_bounds__(256) void cast_f32_bf16(const float* __restrict__ in,
                                                     unsigned short* __restrict__ out, int n8) {
  int idx = blockIdx.x * 256 + threadIdx.x;
  if (idx >= n8) return;
  const float4* p = (const float4*)(in + (size_t)idx * 8);
  float4 a = p[0], b = p[1];
  unsigned short u[8];
  u[0]=f2bf(a.x); u[1]=f2bf(a.y); u[2]=f2bf(a.z); u[3]=f2bf(a.w);
  u[4]=f2bf(b.x); u[5]=f2bf(b.y); u[6]=f2bf(b.z); u[7]=f2bf(b.w);
  *(uint4*)(out + (size_t)idx * 8) = *(uint4*)u;
}

// ================= transpose + cast: in[R][C] f32 -> out[C][R] bf16 =================
__global__ __launch_bounds__(256) void transpose_cast(const float* __restrict__ in,
                                                      unsigned short* __restrict__ out,
                                                      int R, int C) {
  __shared__ float tile[64][65];
  const int tid = threadIdx.x;
  const int c0 = blockIdx.x * 64, r0 = blockIdx.y * 64;
  #pragma unroll
  for (int it = 0; it < 4; ++it) {
    int idx = tid + it * 256;
    int row = idx >> 4, c4 = (idx & 15) * 4;
    float4 v = *(const float4*)(in + (size_t)(r0 + row) * C + c0 + c4);
    tile[row][c4 + 0] = v.x; tile[row][c4 + 1] = v.y;
    tile[row][c4 + 2] = v.z; tile[row][c4 + 3] = v.w;
  }
  __syncthreads();
  #pragma unroll
  for (int it = 0; it < 4; ++it) {
    int idx = tid + it * 256;
    int orow = idx >> 4, r4 = (idx & 15) * 4;
    ushort4 u;
    u.x = f2bf(tile[r4 + 0][orow]);
    u.y = f2bf(tile[r4 + 1][orow]);
    u.z = f2bf(tile[r4 + 2][orow]);
    u.w = f2bf(tile[r4 + 3][orow]);
    *(ushort4*)(out + (size_t)(c0 + orow) * R + r0 + r4) = u;
  }
}

// ================= bf16 transpose per (b,h): in[b*T + t][h*DF + d] -> out[(b*H+h)*DF + d][t] =================
__global__ __launch_bounds__(256) void bt_transpose(const unsigned short* __restrict__ in,
                                                    unsigned short* __restrict__ out,
                                                    int inW, int DF) {
  __shared__ unsigned short tile[64][65];
  const int tid = threadIdx.x;
  const int t0 = blockIdx.x * 64, c0 = blockIdx.y * 64;
  const int b = blockIdx.z >> 3, h = blockIdx.z & 7;
  #pragma unroll
  for (int it = 0; it < 2; ++it) {
    int idx = tid + it * 256;
    int tr = idx >> 3, tc0 = (idx & 7) * 8;
    uint4 v = *(const uint4*)(in + (size_t)(b * 2048 + t0 + tr) * inW + h * DF + c0 + tc0);
    const unsigned short* u = (const unsigned short*)&v;
    #pragma unroll
    for (int j = 0; j < 8; ++j) tile[tr][tc0 + j] = u[j];
  }
  __syncthreads();
  #pragma unroll
  for (int it = 0; it < 2; ++it) {
    int idx = tid + it * 256;
    int od = idx >> 3, ot0 = (idx & 7) * 8;
    unsigned short u[8];
    #pragma unroll
    for (int j = 0; j < 8; ++j) u[j] = tile[ot0 + j][od];
    *(uint4*)(out + ((size_t)blockIdx.z * DF + c0 + od) * 2048 + t0 + ot0) = *(uint4*)u;
  }
}

// ================= gk projection: log_sigmoid(x @ Wgk + bgk)/16, all fp32 =================
__global__ __launch_bounds__(256) void gk_proj(const float* __restrict__ x,
                                               const float* __restrict__ Wgk,
                                               const float* __restrict__ bgk,
                                               float* __restrict__ gk) {
  const int row = blockIdx.x, tid = threadIdx.x;
  const float* xr = x + (size_t)row * HIDD;
  float acc[8];
  #pragma unroll
  for (int h = 0; h < 8; ++h) acc[h] = 0.f;
  for (int i = tid; i < HIDD; i += 256) {
    float xv = xr[i];
    const float4* wr = (const float4*)(Wgk + (size_t)i * 8);
    float4 w0 = wr[0], w1 = wr[1];
    acc[0] += xv * w0.x; acc[1] += xv * w0.y; acc[2] += xv * w0.z; acc[3] += xv * w0.w;
    acc[4] += xv * w1.x; acc[5] += xv * w1.y; acc[6] += xv * w1.z; acc[7] += xv * w1.w;
  }
  #pragma unroll
  for (int off = 32; off; off >>= 1) {
    #pragma unroll
    for (int h = 0; h < 8; ++h) acc[h] += __shfl_xor(acc[h], off, 64);
  }
  __shared__ float red[4][8];
  if ((tid & 63) == 0) {
    #pragma unroll
    for (int h = 0; h < 8; ++h) red[tid >> 6][h] = acc[h];
  }
  __syncthreads();
  if (tid < 8) {
    float z = red[0][tid] + red[1][tid] + red[2][tid] + red[3][tid] + bgk[tid];
    float ls = fminf(z, 0.f) - log1pf(__expf(-fabsf(z)));
    gk[(size_t)row * 8 + tid] = ls * (1.0f / 16.0f);
  }
}

// ================= bf16 GEMM (m97 structure): C[M][N] = A[M][K] * BT[N][K]^T =================
// 128x128 tile, BK=64, global_load_lds w16 with source-side XOR swizzle, 2-barrier loop.
template<int OUT_BF16>
__global__ __launch_bounds__(256, 2) void gemm_bt(const unsigned short* __restrict__ A,
                                                  const unsigned short* __restrict__ BT,
                                                  void* __restrict__ C,
                                                  int M, int N, int K) {
  __shared__ unsigned short smem[16384];  // As = [0,8192), Bs = [8192,16384)  (32KB)
  unsigned short* As = smem;
  unsigned short* Bs = smem + 8192;
  const int tid = threadIdx.x, l = tid & 63;
  const int l15 = l & 15, l4 = l >> 4;
  const int w = tid >> 6, wm = w >> 1, wn = w & 1;
  const int m0 = blockIdx.y * 128, n0 = blockIdx.x * 128;
  const int nk = K >> 6;

  fx4 zero = {0.f, 0.f, 0.f, 0.f};
  fx4 acc[4][4];
  #pragma unroll
  for (int mi = 0; mi < 4; ++mi)
    #pragma unroll
    for (int ni = 0; ni < 4; ++ni) acc[mi][ni] = zero;

  // per-lane staging geometry: chunk = (w*4+i)*64 + l; row = chunk>>3; swizzled source octet
  const int srow[4] = { (w*4+0)*8 + (l>>3), (w*4+1)*8 + (l>>3), (w*4+2)*8 + (l>>3), (w*4+3)*8 + (l>>3) };
  const int soct[4] = { (l&7) ^ (srow[0]&7), (l&7) ^ (srow[1]&7), (l&7) ^ (srow[2]&7), (l&7) ^ (srow[3]&7) };

  for (int kt = 0; kt < nk; ++kt) {
    #pragma unroll
    for (int i = 0; i < 4; ++i) {
      gload16(A  + (size_t)(m0 + srow[i]) * K + kt * 64 + soct[i] * 8, As + (w*4+i)*512);
      gload16(BT + (size_t)(n0 + srow[i]) * K + kt * 64 + soct[i] * 8, Bs + (w*4+i)*512);
    }
    __syncthreads();  // drains vmcnt -> tile ready
    #pragma unroll
    for (int ks = 0; ks < 2; ++ks) {
      s16x8 af[4], bf[4];
      #pragma unroll
      for (int i = 0; i < 4; ++i) {
        int arow = wm * 64 + i * 16 + l15;
        af[i] = *(const s16x8*)(As + arow * 64 + (((ks*4 + l4) ^ (arow & 7)) << 3));
        int brow = wn * 64 + i * 16 + l15;
        bf[i] = *(const s16x8*)(Bs + brow * 64 + (((ks*4 + l4) ^ (brow & 7)) << 3));
      }
      #pragma unroll
      for (int mi = 0; mi < 4; ++mi)
        #pragma unroll
        for (int ni = 0; ni < 4; ++ni)
          acc[mi][ni] = __builtin_amdgcn_mfma_f32_16x16x32_bf16(af[mi], bf[ni], acc[mi][ni], 0, 0, 0);
    }
    __syncthreads();  // reads done before next stage overwrites
  }

  if (OUT_BF16) {
    // LDS-bounce epilogue: 32KB C-tile [128][128] bf16, XOR-swizzled 16B chunks, coalesced b128 stores
    #pragma unroll
    for (int mi = 0; mi < 4; ++mi)
      #pragma unroll
      for (int r = 0; r < 4; ++r) {
        int row = wm * 64 + mi * 16 + l4 * 4 + r;
        #pragma unroll
        for (int ni = 0; ni < 4; ++ni) {
          int col = wn * 64 + ni * 16 + l15;
          smem[row * 128 + (((col >> 3) ^ (row & 7)) << 3) + (col & 7)] = f2bf(acc[mi][ni][r]);
        }
      }
    __syncthreads();
    #pragma unroll
    for (int it = 0; it < 8; ++it) {
      int idx = tid + it * 256;
      int row = idx >> 4, cl = idx & 15;
      uint4 vv = *(const uint4*)(smem + row * 128 + ((cl ^ (row & 7)) << 3));
      *(uint4*)((unsigned short*)C + (size_t)(m0 + row) * N + n0 + cl * 8) = vv;
    }
  } else {
    #pragma unroll
    for (int mi = 0; mi < 4; ++mi)
      #pragma unroll
      for (int r = 0; r < 4; ++r) {
        const size_t row = m0 + wm * 64 + mi * 16 + l4 * 4 + r;
        #pragma unroll
        for (int ni = 0; ni < 4; ++ni) {
          const int col = n0 + wn * 64 + ni * 16 + l15;
          ((float*)C)[row * N + col] = acc[mi][ni][r];
        }
      }
  }
}

// ================= chunked GLA scan (v2: transposed-global staging, no LDS scatter) =================
// grid = B*H*(DV/64) = 128 blocks; 4 waves; wave w owns dv slice [w*16, w*16+16).
// S[256dk][64dv] fp32 in MFMA accumulators (16 frags/lane).
// LDS: skbuf 32KB shared between ST[64dv][256dk] (phase 0-1) and kT[256dk][64cc] (phase 2-3).
__global__ __launch_bounds__(256, 1) void gla_kernel(const unsigned short* __restrict__ qb,
                                                     const unsigned short* __restrict__ kb,
                                                     const unsigned short* __restrict__ ktg,
                                                     const unsigned short* __restrict__ vtg,
                                                     const float* __restrict__ gkw,
                                                     unsigned short* __restrict__ oat) {
  const int blk = blockIdx.x;
  const int dvb = blk & 7, h = (blk >> 3) & 7, b = blk >> 6;
  const int dv0 = dvb * 64;
  const int tid = threadIdx.x, l = tid & 63, w = tid >> 6;
  const int l15 = l & 15, l4 = l >> 4;

  __shared__ __align__(16) unsigned short skbuf[16384]; // 32KB: ST then kT
  __shared__ __align__(16) unsigned short vTs[4096];    // 8KB: vT [64dv][64cc] swizzled
  __shared__ __align__(16) unsigned short Als[4096];    // 8KB: A [64t][64cc] swizzled
  __shared__ float gis[64], els[64], eis[64];

  fx4 zero = {0.f, 0.f, 0.f, 0.f};
  fx4 S[16];
  #pragma unroll
  for (int t = 0; t < 16; ++t) S[t] = zero;

  const unsigned short* qbase = qb + (size_t)b * TSEQ * HDKD + h * DKD;
  const unsigned short* kbase = kb + (size_t)b * TSEQ * HDKD + h * DKD;
  const unsigned short* ktg_bh = ktg + (size_t)(b * 8 + h) * DKD * TSEQ;
  const unsigned short* vtg_bh = vtg + ((size_t)(b * 8 + h) * DVD + dv0) * TSEQ;
  const float*  gbase = gkw + (size_t)b * TSEQ * NH + h;
  unsigned short* obase = oat + (size_t)b * TSEQ * HDVD + h * DVD + dv0;

  const int dvl = w * 16 + l15;

  for (int c = 0; c < NCH; ++c) {
    const int t0 = c * CHK;

    // ---- P0: issue vT stage; wave0 cumsum -> gis/els/eis; ST(bf16) <- S accumulators ----
    #pragma unroll
    for (int i = 0; i < 2; ++i) {
      int c16 = (w * 2 + i) * 64 + l;
      int dv = c16 >> 3, os = c16 & 7;
      gload16(vtg_bh + (size_t)dv * TSEQ + t0 + ((os ^ (dv & 7)) << 3), vTs + (w * 2 + i) * 512);
    }
    if (tid < 64) {
      float xg = gbase[(size_t)(t0 + tid) * NH];
      #pragma unroll
      for (int off = 1; off < 64; off <<= 1) {
        float y = __shfl_up(xg, off, 64);
        if (l >= off) xg += y;
      }
      gis[tid] = xg;
      float gl = __shfl(xg, 63, 64);
      els[tid] = __expf(gl - xg);
      eis[tid] = 0.0625f * __expf(xg);
    }
    #pragma unroll
    for (int t = 0; t < 16; ++t) {
      const int dk0 = t * 16 + l4 * 4;
      ushort4 p;
      p.x = f2bf(S[t].x); p.y = f2bf(S[t].y); p.z = f2bf(S[t].z); p.w = f2bf(S[t].w);
      *(ushort4*)(skbuf + dvl * 256 + (((dk0 >> 3) ^ (dvl & 7)) << 3) + (dk0 & 7)) = p;
    }
    __syncthreads();

    // ---- P1: O1 = q @ S^T-frags;  Araw = q @ k^T (k rows from global) ----
    s16x8 kf[8], stf[8];
    {
      const unsigned short* krow = kbase + (size_t)(t0 + dvl) * HDKD;
      #pragma unroll
      for (int ks = 0; ks < 8; ++ks) {
        kf[ks] = *(const s16x8*)(krow + ks * 32 + l4 * 8);
        stf[ks] = *(const s16x8*)(skbuf + dvl * 256 + (((ks * 4 + l4) ^ (dvl & 7)) << 3));
      }
    }
    fx4 o1[4], ar[4];
    #pragma unroll
    for (int ct = 0; ct < 4; ++ct) {
      o1[ct] = zero; ar[ct] = zero;
      const unsigned short* qrow = qbase + (size_t)(t0 + ct * 16 + l15) * HDKD;
      #pragma unroll
      for (int ks = 0; ks < 8; ++ks) {
        s16x8 qf = *(const s16x8*)(qrow + ks * 32 + l4 * 8);
        o1[ct] = __builtin_amdgcn_mfma_f32_16x16x32_bf16(qf, stf[ks], o1[ct], 0, 0, 0);
        ar[ct] = __builtin_amdgcn_mfma_f32_16x16x32_bf16(qf, kf[ks], ar[ct], 0, 0, 0);
      }
    }
    {
      const int j = dvl;
      const float gj = gis[j];
      #pragma unroll
      for (int ct = 0; ct < 4; ++ct) {
        #pragma unroll
        for (int r = 0; r < 4; ++r) {
          const int i = ct * 16 + l4 * 4 + r;
          float av = (i >= j) ? ar[ct][r] * 0.0625f * __expf(gis[i] - gj) : 0.f;
          Als[i * 64 + (((j >> 3) ^ (i & 7)) << 3) + (j & 7)] = f2bf(av);
          o1[ct][r] *= eis[i];
        }
      }
    }
    __syncthreads();

    // ---- P2: issue kT stage into skbuf; o = O1 + A @ vT-frags; store o ----
    #pragma unroll
    for (int i = 0; i < 8; ++i) {
      int c16 = (w * 8 + i) * 64 + l;
      int dk = c16 >> 3, os = c16 & 7;
      gload16(ktg_bh + (size_t)dk * TSEQ + t0 + ((os ^ (dk & 7)) << 3), skbuf + (w * 8 + i) * 512);
    }
    s16x8 vf[2], vf2[2];
    #pragma unroll
    for (int ks = 0; ks < 2; ++ks)
      vf[ks] = *(const s16x8*)(vTs + dvl * 64 + (((ks * 4 + l4) ^ (dvl & 7)) << 3));
    #pragma unroll
    for (int ks = 0; ks < 2; ++ks)
      #pragma unroll
      for (int j = 0; j < 8; ++j) {
        float e = els[ks * 32 + l4 * 8 + j];
        vf2[ks][j] = (short)f2bf(bf2f((unsigned short)vf[ks][j]) * e);
      }
    #pragma unroll
    for (int ct = 0; ct < 4; ++ct) {
      const int i = ct * 16 + l15;
      #pragma unroll
      for (int ks = 0; ks < 2; ++ks) {
        s16x8 af = *(const s16x8*)(Als + i * 64 + (((ks * 4 + l4) ^ (i & 7)) << 3));
        o1[ct] = __builtin_amdgcn_mfma_f32_16x16x32_bf16(af, vf[ks], o1[ct], 0, 0, 0);
      }
      #pragma unroll
      for (int r = 0; r < 4; ++r) {
        const int tt = t0 + ct * 16 + l4 * 4 + r;
        obase[(size_t)tt * HDVD + dvl] = f2bf(o1[ct][r]);
      }
    }
    __syncthreads();  // drains kT gloads

    // ---- P3: S = exp(gl)*S + kT-frags @ (vT*els)-frags ----
    {
      const float egl = __expf(gis[63]);
      #pragma unroll
      for (int t = 0; t < 16; ++t) {
        S[t].x *= egl; S[t].y *= egl; S[t].z *= egl; S[t].w *= egl;
        const int dk = t * 16 + l15;
        #pragma unroll
        for (int ks = 0; ks < 2; ++ks) {
          s16x8 ktf = *(const s16x8*)(skbuf + dk * 64 + (((ks * 4 + l4) ^ (dk & 7)) << 3));
          S[t] = __builtin_amdgcn_mfma_f32_16x16x32_bf16(ktf, vf2[ks], S[t], 0, 0, 0);
        }
      }
    }
    __syncthreads();  // protect skbuf/vTs/Als/gis before next chunk
  }
}

// ================= fused RMSnorm * norm_w * silu(g), in-place on o =================
__global__ __launch_bounds__(256) void norm_gate(unsigned short* __restrict__ o,
                                                 const unsigned short* __restrict__ g,
                                                 const float* __restrict__ nw) {
  const int seg = blockIdx.x * 4 + (threadIdx.x >> 6);
  const int l = threadIdx.x & 63;
  const size_t base = (size_t)seg * 512 + l * 8;
  uint4 ov = *(const uint4*)(o + base);
  const unsigned short* ou = (const unsigned short*)&ov;
  float f[8], ss = 0.f;
  #pragma unroll
  for (int j = 0; j < 8; ++j) { f[j] = bf2f(ou[j]); ss += f[j] * f[j]; }
  #pragma unroll
  for (int off = 32; off; off >>= 1) ss += __shfl_xor(ss, off, 64);
  const float rms = rsqrtf(ss * (1.0f / 512.0f) + 1e-5f);
  uint4 gv = *(const uint4*)(g + base);
  const unsigned short* gu = (const unsigned short*)&gv;
  const float4 w0 = *(const float4*)(nw + l * 8);
  const float4 w1 = *(const float4*)(nw + l * 8 + 4);
  float wv[8] = {w0.x, w0.y, w0.z, w0.w, w1.x, w1.y, w1.z, w1.w};
  unsigned short ru[8];
  #pragma unroll
  for (int j = 0; j < 8; ++j) {
    float gf = bf2f(gu[j]);
    float si = gf / (1.f + __expf(-gf));
    ru[j] = f2bf(f[j] * rms * wv[j] * si);
  }
  *(uint4*)(o + base) = *(uint4*)ru;
}

// ================= launch =================
extern "C" void kernel_launch(void* const* d_in, const int* in_sizes, int n_in,
                              void* d_out, int out_size, void* d_ws, size_t ws_size,
                              hipStream_t stream) {
  (void)in_sizes; (void)n_in; (void)out_size; (void)ws_size;
  const float* x   = (const float*)d_in[0];
  const float* Wq  = (const float*)d_in[1];
  const float* Wk  = (const float*)d_in[2];
  const float* Wv  = (const float*)d_in[3];
  const float* Wg  = (const float*)d_in[4];
  const float* Wgk = (const float*)d_in[5];
  const float* bgk = (const float*)d_in[6];
  const float* Wo  = (const float*)d_in[7];
  const float* nw  = (const float*)d_in[8];

  char* ws = (char*)d_ws;
  const size_t MB = 1024 * 1024;
  unsigned short* xb  = (unsigned short*)(ws + 0);        // 16MB
  unsigned short* wqT = (unsigned short*)(ws + 16*MB);    // 8MB
  unsigned short* wkT = (unsigned short*)(ws + 24*MB);    // 8MB
  unsigned short* wvT = (unsigned short*)(ws + 32*MB);    // 16MB
  unsigned short* wgT = (unsigned short*)(ws + 48*MB);    // 16MB
  unsigned short* woT = (unsigned short*)(ws + 64*MB);    // 16MB
  unsigned short* qb  = (unsigned short*)(ws + 80*MB);    // 16MB
  unsigned short* kb  = (unsigned short*)(ws + 96*MB);    // 16MB
  unsigned short* vb  = (unsigned short*)(ws + 112*MB);   // 32MB
  unsigned short* gb  = (unsigned short*)(ws + 144*MB);   // 32MB
  float* gkb          = (float*)(ws + 176*MB);            // 128KB
  // aliases (dead-after-use regions):
  unsigned short* ktg = wqT;   // 16MB over wqT+wkT (dead after k-GEMM)
  unsigned short* vtg = wvT;   // 32MB over wvT+wgT (dead after g-GEMM)
  unsigned short* oat = vb;    // 32MB over vb (dead after v-transpose)

  cast_f32_bf16<<<4096, 256, 0, stream>>>(x, xb, 4096 * 2048 / 8);
  transpose_cast<<<dim3(32, 32), 256, 0, stream>>>(Wq, wqT, 2048, 2048);
  transpose_cast<<<dim3(32, 32), 256, 0, stream>>>(Wk, wkT, 2048, 2048);
  transpose_cast<<<dim3(64, 32), 256, 0, stream>>>(Wv, wvT, 2048, 4096);
  transpose_cast<<<dim3(64, 32), 256, 0, stream>>>(Wg, wgT, 2048, 4096);
  transpose_cast<<<dim3(32, 64), 256, 0, stream>>>(Wo, woT, 4096, 2048);
  gk_proj<<<4096, 256, 0, stream>>>(x, Wgk, bgk, gkb);

  gemm_bt<1><<<dim3(16, 32), 256, 0, stream>>>(xb, wqT, qb, 4096, 2048, 2048);
  gemm_bt<1><<<dim3(16, 32), 256, 0, stream>>>(xb, wkT, kb, 4096, 2048, 2048);
  gemm_bt<1><<<dim3(32, 32), 256, 0, stream>>>(xb, wvT, vb, 4096, 4096, 2048);
  gemm_bt<1><<<dim3(32, 32), 256, 0, stream>>>(xb, wgT, gb, 4096, 4096, 2048);

  bt_transpose<<<dim3(32, 4, 16), 256, 0, stream>>>(kb, ktg, 2048, 256);  // k -> kT_g (over wqT/wkT)
  bt_transpose<<<dim3(32, 8, 16), 256, 0, stream>>>(vb, vtg, 4096, 512);  // v -> vT_g (over wvT/wgT)

  gla_kernel<<<128, 256, 0, stream>>>(qb, kb, ktg, vtg, gkb, oat);
  norm_gate<<<8192, 256, 0, stream>>>(oat, gb, nw);

  gemm_bt<0><<<dim3(16, 32), 256, 0, stream>>>(oat, woT, d_out, 4096, 2048, 4096);
}

// Round 6
// 726.909 us; speedup vs baseline: 3.4973x; 1.1750x over previous
//
#include <hip/hip_runtime.h>
#include <cstdint>
#include <cstddef>

// ---- problem constants ----
#define NB 2
#define TSEQ 2048
#define HIDD 2048
#define NH 8
#define DKD 256
#define DVD 512
#define CHK 64
#define NCH 32
#define HDKD 2048
#define HDVD 4096

typedef __attribute__((ext_vector_type(8))) short s16x8;  // 8 bf16 (4 VGPRs)
typedef __attribute__((ext_vector_type(4))) float fx4;    // MFMA accum

__device__ __forceinline__ float bf2f(unsigned short u) {
  union { float f; uint32_t i; } x; x.i = ((uint32_t)u) << 16; return x.f;
}
__device__ __forceinline__ unsigned short f2bf(float f) {
  union { float f; uint32_t i; } x; x.f = f;
  uint32_t r = (x.i + 0x7fffu + ((x.i >> 16) & 1u)) >> 16;
  return (unsigned short)r;
}

// async global->LDS, 16B per lane; LDS dest = wave-uniform base + lane*16
__device__ __forceinline__ void gload16(const unsigned short* g, unsigned short* l) {
  __builtin_amdgcn_global_load_lds(
      (const __attribute__((address_space(1))) void*)g,
      (__attribute__((address_space(3))) void*)l, 16, 0, 0);
}

// ================= elementwise f32 -> bf16 cast =================
__global__ __launch_bounds__(256) void cast_f32_bf16(const float* __restrict__ in,
                                                     unsigned short* __restrict__ out, int n8) {
  int idx = blockIdx.x * 256 + threadIdx.x;
  if (idx >= n8) return;
  const float4* p = (const float4*)(in + (size_t)idx * 8);
  float4 a = p[0], b = p[1];
  unsigned short u[8];
  u[0]=f2bf(a.x); u[1]=f2bf(a.y); u[2]=f2bf(a.z); u[3]=f2bf(a.w);
  u[4]=f2bf(b.x); u[5]=f2bf(b.y); u[6]=f2bf(b.z); u[7]=f2bf(b.w);
  *(uint4*)(out + (size_t)idx * 8) = *(uint4*)u;
}

// ================= transpose + cast: in[R][C] f32 -> out[C][R] bf16 =================
__global__ __launch_bounds__(256) void transpose_cast(const float* __restrict__ in,
                                                      unsigned short* __restrict__ out,
                                                      int R, int C) {
  __shared__ float tile[64][65];
  const int tid = threadIdx.x;
  const int c0 = blockIdx.x * 64, r0 = blockIdx.y * 64;
  #pragma unroll
  for (int it = 0; it < 4; ++it) {
    int idx = tid + it * 256;
    int row = idx >> 4, c4 = (idx & 15) * 4;
    float4 v = *(const float4*)(in + (size_t)(r0 + row) * C + c0 + c4);
    tile[row][c4 + 0] = v.x; tile[row][c4 + 1] = v.y;
    tile[row][c4 + 2] = v.z; tile[row][c4 + 3] = v.w;
  }
  __syncthreads();
  #pragma unroll
  for (int it = 0; it < 4; ++it) {
    int idx = tid + it * 256;
    int orow = idx >> 4, r4 = (idx & 15) * 4;
    ushort4 u;
    u.x = f2bf(tile[r4 + 0][orow]);
    u.y = f2bf(tile[r4 + 1][orow]);
    u.z = f2bf(tile[r4 + 2][orow]);
    u.w = f2bf(tile[r4 + 3][orow]);
    *(ushort4*)(out + (size_t)(c0 + orow) * R + r0 + r4) = u;
  }
}

// ================= bf16 transpose per (b,h): in[b*T + t][h*DF + d] -> out[(b*H+h)*DF + d][t] =================
__global__ __launch_bounds__(256) void bt_transpose(const unsigned short* __restrict__ in,
                                                    unsigned short* __restrict__ out,
                                                    int inW, int DF) {
  __shared__ unsigned short tile[64][65];
  const int tid = threadIdx.x;
  const int t0 = blockIdx.x * 64, c0 = blockIdx.y * 64;
  const int b = blockIdx.z >> 3, h = blockIdx.z & 7;
  #pragma unroll
  for (int it = 0; it < 2; ++it) {
    int idx = tid + it * 256;
    int tr = idx >> 3, tc0 = (idx & 7) * 8;
    uint4 v = *(const uint4*)(in + (size_t)(b * 2048 + t0 + tr) * inW + h * DF + c0 + tc0);
    const unsigned short* u = (const unsigned short*)&v;
    #pragma unroll
    for (int j = 0; j < 8; ++j) tile[tr][tc0 + j] = u[j];
  }
  __syncthreads();
  #pragma unroll
  for (int it = 0; it < 2; ++it) {
    int idx = tid + it * 256;
    int od = idx >> 3, ot0 = (idx & 7) * 8;
    unsigned short u[8];
    #pragma unroll
    for (int j = 0; j < 8; ++j) u[j] = tile[ot0 + j][od];
    *(uint4*)(out + ((size_t)blockIdx.z * DF + c0 + od) * 2048 + t0 + ot0) = *(uint4*)u;
  }
}

// ================= gk projection: log_sigmoid(x @ Wgk + bgk)/16, all fp32 =================
__global__ __launch_bounds__(256) void gk_proj(const float* __restrict__ x,
                                               const float* __restrict__ Wgk,
                                               const float* __restrict__ bgk,
                                               float* __restrict__ gk) {
  const int row = blockIdx.x, tid = threadIdx.x;
  const float* xr = x + (size_t)row * HIDD;
  float acc[8];
  #pragma unroll
  for (int h = 0; h < 8; ++h) acc[h] = 0.f;
  for (int i = tid; i < HIDD; i += 256) {
    float xv = xr[i];
    const float4* wr = (const float4*)(Wgk + (size_t)i * 8);
    float4 w0 = wr[0], w1 = wr[1];
    acc[0] += xv * w0.x; acc[1] += xv * w0.y; acc[2] += xv * w0.z; acc[3] += xv * w0.w;
    acc[4] += xv * w1.x; acc[5] += xv * w1.y; acc[6] += xv * w1.z; acc[7] += xv * w1.w;
  }
  #pragma unroll
  for (int off = 32; off; off >>= 1) {
    #pragma unroll
    for (int h = 0; h < 8; ++h) acc[h] += __shfl_xor(acc[h], off, 64);
  }
  __shared__ float red[4][8];
  if ((tid & 63) == 0) {
    #pragma unroll
    for (int h = 0; h < 8; ++h) red[tid >> 6][h] = acc[h];
  }
  __syncthreads();
  if (tid < 8) {
    float z = red[0][tid] + red[1][tid] + red[2][tid] + red[3][tid] + bgk[tid];
    float ls = fminf(z, 0.f) - log1pf(__expf(-fabsf(z)));
    gk[(size_t)row * 8 + tid] = ls * (1.0f / 16.0f);
  }
}

// ================= bf16 GEMM (m97 structure): C[M][N] = A[M][K] * BT[N][K]^T =================
// 128x128 tile, BK=64, global_load_lds w16 with source-side XOR swizzle, 2-barrier loop.
template<int OUT_BF16>
__global__ __launch_bounds__(256, 2) void gemm_bt(const unsigned short* __restrict__ A,
                                                  const unsigned short* __restrict__ BT,
                                                  void* __restrict__ C,
                                                  int M, int N, int K) {
  __shared__ unsigned short smem[16384];  // As = [0,8192), Bs = [8192,16384)  (32KB)
  unsigned short* As = smem;
  unsigned short* Bs = smem + 8192;
  const int tid = threadIdx.x, l = tid & 63;
  const int l15 = l & 15, l4 = l >> 4;
  const int w = tid >> 6, wm = w >> 1, wn = w & 1;
  const int m0 = blockIdx.y * 128, n0 = blockIdx.x * 128;
  const int nk = K >> 6;

  fx4 zero = {0.f, 0.f, 0.f, 0.f};
  fx4 acc[4][4];
  #pragma unroll
  for (int mi = 0; mi < 4; ++mi)
    #pragma unroll
    for (int ni = 0; ni < 4; ++ni) acc[mi][ni] = zero;

  // per-lane staging geometry: chunk = (w*4+i)*64 + l; row = chunk>>3; swizzled source octet
  const int srow[4] = { (w*4+0)*8 + (l>>3), (w*4+1)*8 + (l>>3), (w*4+2)*8 + (l>>3), (w*4+3)*8 + (l>>3) };
  const int soct[4] = { (l&7) ^ (srow[0]&7), (l&7) ^ (srow[1]&7), (l&7) ^ (srow[2]&7), (l&7) ^ (srow[3]&7) };

  for (int kt = 0; kt < nk; ++kt) {
    #pragma unroll
    for (int i = 0; i < 4; ++i) {
      gload16(A  + (size_t)(m0 + srow[i]) * K + kt * 64 + soct[i] * 8, As + (w*4+i)*512);
      gload16(BT + (size_t)(n0 + srow[i]) * K + kt * 64 + soct[i] * 8, Bs + (w*4+i)*512);
    }
    __syncthreads();  // drains vmcnt -> tile ready
    #pragma unroll
    for (int ks = 0; ks < 2; ++ks) {
      s16x8 af[4], bf[4];
      #pragma unroll
      for (int i = 0; i < 4; ++i) {
        int arow = wm * 64 + i * 16 + l15;
        af[i] = *(const s16x8*)(As + arow * 64 + (((ks*4 + l4) ^ (arow & 7)) << 3));
        int brow = wn * 64 + i * 16 + l15;
        bf[i] = *(const s16x8*)(Bs + brow * 64 + (((ks*4 + l4) ^ (brow & 7)) << 3));
      }
      #pragma unroll
      for (int mi = 0; mi < 4; ++mi)
        #pragma unroll
        for (int ni = 0; ni < 4; ++ni)
          acc[mi][ni] = __builtin_amdgcn_mfma_f32_16x16x32_bf16(af[mi], bf[ni], acc[mi][ni], 0, 0, 0);
    }
    __syncthreads();  // reads done before next stage overwrites
  }

  if (OUT_BF16) {
    // LDS-bounce epilogue: 32KB C-tile [128][128] bf16, XOR-swizzled 16B chunks, coalesced b128 stores
    #pragma unroll
    for (int mi = 0; mi < 4; ++mi)
      #pragma unroll
      for (int r = 0; r < 4; ++r) {
        int row = wm * 64 + mi * 16 + l4 * 4 + r;
        #pragma unroll
        for (int ni = 0; ni < 4; ++ni) {
          int col = wn * 64 + ni * 16 + l15;
          smem[row * 128 + (((col >> 3) ^ (row & 7)) << 3) + (col & 7)] = f2bf(acc[mi][ni][r]);
        }
      }
    __syncthreads();
    #pragma unroll
    for (int it = 0; it < 8; ++it) {
      int idx = tid + it * 256;
      int row = idx >> 4, cl = idx & 15;
      uint4 vv = *(const uint4*)(smem + row * 128 + ((cl ^ (row & 7)) << 3));
      *(uint4*)((unsigned short*)C + (size_t)(m0 + row) * N + n0 + cl * 8) = vv;
    }
  } else {
    #pragma unroll
    for (int mi = 0; mi < 4; ++mi)
      #pragma unroll
      for (int r = 0; r < 4; ++r) {
        const size_t row = m0 + wm * 64 + mi * 16 + l4 * 4 + r;
        #pragma unroll
        for (int ni = 0; ni < 4; ++ni) {
          const int col = n0 + wn * 64 + ni * 16 + l15;
          ((float*)C)[row * N + col] = acc[mi][ni][r];
        }
      }
  }
}

// ================= chunked GLA scan (v3: fully LDS-staged q/k, deep prefetch) =================
// grid = B*H*(DV/64) = 128 blocks; bh = blk&15 so the 8 dv-siblings of one (b,h)
// share blk%8 -> same XCD L2 (q/k/kT fetched once per (b,h), not 8x).
// 4 waves; wave w owns dv slice [w*16, w*16+16). S[256dk][64dv] fp32 in accumulators.
// LDS (121KB): skbuf 32K (ST phase0-1 / kT phase2-3), qs 32K, kst 32K, vTs 2x8K, Als 8K.
// q/k/vT for chunk c+1 are staged (async DMA) at P3(c) start, hidden under S-update MFMAs.
__global__ __launch_bounds__(256, 1) void gla_kernel(const unsigned short* __restrict__ qb,
                                                     const unsigned short* __restrict__ kb,
                                                     const unsigned short* __restrict__ ktg,
                                                     const unsigned short* __restrict__ vtg,
                                                     const float* __restrict__ gkw,
                                                     unsigned short* __restrict__ oat) {
  const int blk = blockIdx.x;
  const int bh = blk & 15, dvb = blk >> 4;
  const int b = bh >> 3, h = bh & 7;
  const int dv0 = dvb * 64;
  const int tid = threadIdx.x, l = tid & 63, w = tid >> 6;
  const int l15 = l & 15, l4 = l >> 4;

  __shared__ __align__(16) unsigned short skbuf[16384];  // 32KB: ST then kT
  __shared__ __align__(16) unsigned short qs[16384];     // 32KB: q tile [64][256] swz
  __shared__ __align__(16) unsigned short kst[16384];    // 32KB: k tile [64][256] swz
  __shared__ __align__(16) unsigned short vTs[2][4096];  // 2x8KB: vT [64dv][64cc] swz dbuf
  __shared__ __align__(16) unsigned short Als[4096];     // 8KB: A [64t][64cc] swz
  __shared__ float gis[64], els[64], eis[64];

  fx4 zero = {0.f, 0.f, 0.f, 0.f};
  fx4 S[16];
  #pragma unroll
  for (int t = 0; t < 16; ++t) S[t] = zero;

  const unsigned short* qbase = qb + (size_t)b * TSEQ * HDKD + h * DKD;
  const unsigned short* kbase = kb + (size_t)b * TSEQ * HDKD + h * DKD;
  const unsigned short* ktg_bh = ktg + (size_t)(b * 8 + h) * DKD * TSEQ;
  const unsigned short* vtg_bh = vtg + ((size_t)(b * 8 + h) * DVD + dv0) * TSEQ;
  const float*  gbase = gkw + (size_t)b * TSEQ * NH + h;
  unsigned short* obase = oat + (size_t)b * TSEQ * HDVD + h * DVD + dv0;

  const int dvl = w * 16 + l15;

  // ---- staging lambdas (per-wave slices; LDS linear dest, source-side XOR swizzle) ----
  auto stage_qk = [&](int t0) {
    #pragma unroll
    for (int i = 0; i < 8; ++i) {
      int s = (w * 8 + i) * 64 + l;          // slot 0..2047; row 0..63, 32 octets/row
      int row = s >> 5, o = s & 31;
      int osw = o ^ (row & 7);
      gload16(qbase + (size_t)(t0 + row) * HDKD + (osw << 3), qs  + (w * 8 + i) * 512);
      gload16(kbase + (size_t)(t0 + row) * HDKD + (osw << 3), kst + (w * 8 + i) * 512);
    }
  };
  auto stage_v = [&](int t0, int buf) {
    #pragma unroll
    for (int i = 0; i < 2; ++i) {
      int s = (w * 2 + i) * 64 + l;          // slot 0..511; dv row 0..63, 8 octets/row
      int dv = s >> 3, os = s & 7;
      gload16(vtg_bh + (size_t)dv * TSEQ + t0 + ((os ^ (dv & 7)) << 3), vTs[buf] + (w * 2 + i) * 512);
    }
  };

  // prologue: stage chunk 0 q/k/vT (drained at P0(0)-end barrier)
  stage_qk(0);
  stage_v(0, 0);

  for (int c = 0; c < NCH; ++c) {
    const int t0 = c * CHK;

    // ---- P0: wave0 cumsum -> gis/els/eis; ST(bf16) <- S accumulators ----
    if (tid < 64) {
      float xg = gbase[(size_t)(t0 + tid) * NH];
      #pragma unroll
      for (int off = 1; off < 64; off <<= 1) {
        float y = __shfl_up(xg, off, 64);
        if (l >= off) xg += y;
      }
      gis[tid] = xg;
      float gl = __shfl(xg, 63, 64);
      els[tid] = __expf(gl - xg);
      eis[tid] = 0.0625f * __expf(xg);
    }
    #pragma unroll
    for (int t = 0; t < 16; ++t) {
      const int dk0 = t * 16 + l4 * 4;
      ushort4 p;
      p.x = f2bf(S[t].x); p.y = f2bf(S[t].y); p.z = f2bf(S[t].z); p.w = f2bf(S[t].w);
      *(ushort4*)(skbuf + dvl * 256 + (((dk0 >> 3) ^ (dvl & 7)) << 3) + (dk0 & 7)) = p;
    }
    __syncthreads();

    // ---- P1: O1 = q @ S^T-frags;  Araw = q @ k^T  (q,k from LDS) ----
    s16x8 kf[8], stf[8];
    #pragma unroll
    for (int ks = 0; ks < 8; ++ks) {
      kf[ks]  = *(const s16x8*)(kst   + dvl * 256 + (((ks * 4 + l4) ^ (dvl & 7)) << 3));
      stf[ks] = *(const s16x8*)(skbuf + dvl * 256 + (((ks * 4 + l4) ^ (dvl & 7)) << 3));
    }
    fx4 o1[4], ar[4];
    #pragma unroll
    for (int ct = 0; ct < 4; ++ct) {
      o1[ct] = zero; ar[ct] = zero;
      const int qrow = ct * 16 + l15;
      #pragma unroll
      for (int ks = 0; ks < 8; ++ks) {
        s16x8 qf = *(const s16x8*)(qs + qrow * 256 + (((ks * 4 + l4) ^ (l15 & 7)) << 3));
        o1[ct] = __builtin_amdgcn_mfma_f32_16x16x32_bf16(qf, stf[ks], o1[ct], 0, 0, 0);
        ar[ct] = __builtin_amdgcn_mfma_f32_16x16x32_bf16(qf, kf[ks], ar[ct], 0, 0, 0);
      }
    }
    {
      const int j = dvl;
      const float gj = gis[j];
      #pragma unroll
      for (int ct = 0; ct < 4; ++ct) {
        #pragma unroll
        for (int r = 0; r < 4; ++r) {
          const int i = ct * 16 + l4 * 4 + r;
          float av = (i >= j) ? ar[ct][r] * 0.0625f * __expf(gis[i] - gj) : 0.f;
          Als[i * 64 + (((j >> 3) ^ (i & 7)) << 3) + (j & 7)] = f2bf(av);
          o1[ct][r] *= eis[i];
        }
      }
    }
    __syncthreads();

    // ---- P2: issue kT stage into skbuf; o = O1 + A @ vT-frags; store o ----
    #pragma unroll
    for (int i = 0; i < 8; ++i) {
      int c16 = (w * 8 + i) * 64 + l;
      int dk = c16 >> 3, os = c16 & 7;
      gload16(ktg_bh + (size_t)dk * TSEQ + t0 + ((os ^ (dk & 7)) << 3), skbuf + (w * 8 + i) * 512);
    }
    s16x8 vf[2], vf2[2];
    #pragma unroll
    for (int ks = 0; ks < 2; ++ks)
      vf[ks] = *(const s16x8*)(vTs[c & 1] + dvl * 64 + (((ks * 4 + l4) ^ (dvl & 7)) << 3));
    #pragma unroll
    for (int ks = 0; ks < 2; ++ks)
      #pragma unroll
      for (int j = 0; j < 8; ++j) {
        float e = els[ks * 32 + l4 * 8 + j];
        vf2[ks][j] = (short)f2bf(bf2f((unsigned short)vf[ks][j]) * e);
      }
    #pragma unroll
    for (int ct = 0; ct < 4; ++ct) {
      const int i = ct * 16 + l15;
      #pragma unroll
      for (int ks = 0; ks < 2; ++ks) {
        s16x8 af = *(const s16x8*)(Als + i * 64 + (((ks * 4 + l4) ^ (i & 7)) << 3));
        o1[ct] = __builtin_amdgcn_mfma_f32_16x16x32_bf16(af, vf[ks], o1[ct], 0, 0, 0);
      }
      #pragma unroll
      for (int r = 0; r < 4; ++r) {
        const int tt = t0 + ct * 16 + l4 * 4 + r;
        obase[(size_t)tt * HDVD + dvl] = f2bf(o1[ct][r]);
      }
    }
    __syncthreads();  // drains kT gloads

    // ---- P3: issue q/k/vT stages for c+1 (hidden under MFMAs); S = exp(gl)*S + kT' @ v ----
    {
      const int cn = (c + 1 < NCH) ? c + 1 : c;   // last iter re-stages (harmless, never read)
      stage_qk(cn * CHK);
      stage_v(cn * CHK, (c + 1) & 1);
    }
    {
      const float egl = __expf(gis[63]);
      #pragma unroll
      for (int t = 0; t < 16; ++t) {
        S[t].x *= egl; S[t].y *= egl; S[t].z *= egl; S[t].w *= egl;
        const int dk = t * 16 + l15;
        #pragma unroll
        for (int ks = 0; ks < 2; ++ks) {
          s16x8 ktf = *(const s16x8*)(skbuf + dk * 64 + (((ks * 4 + l4) ^ (dk & 7)) << 3));
          S[t] = __builtin_amdgcn_mfma_f32_16x16x32_bf16(ktf, vf2[ks], S[t], 0, 0, 0);
        }
      }
    }
    __syncthreads();  // drains next-chunk stages; protects skbuf before P0(c+1)
  }
}

// ================= fused RMSnorm * norm_w * silu(g), in-place on o =================
__global__ __launch_bounds__(256) void norm_gate(unsigned short* __restrict__ o,
                                                 const unsigned short* __restrict__ g,
                                                 const float* __restrict__ nw) {
  const int seg = blockIdx.x * 4 + (threadIdx.x >> 6);
  const int l = threadIdx.x & 63;
  const size_t base = (size_t)seg * 512 + l * 8;
  uint4 ov = *(const uint4*)(o + base);
  const unsigned short* ou = (const unsigned short*)&ov;
  float f[8], ss = 0.f;
  #pragma unroll
  for (int j = 0; j < 8; ++j) { f[j] = bf2f(ou[j]); ss += f[j] * f[j]; }
  #pragma unroll
  for (int off = 32; off; off >>= 1) ss += __shfl_xor(ss, off, 64);
  const float rms = rsqrtf(ss * (1.0f / 512.0f) + 1e-5f);
  uint4 gv = *(const uint4*)(g + base);
  const unsigned short* gu = (const unsigned short*)&gv;
  const float4 w0 = *(const float4*)(nw + l * 8);
  const float4 w1 = *(const float4*)(nw + l * 8 + 4);
  float wv[8] = {w0.x, w0.y, w0.z, w0.w, w1.x, w1.y, w1.z, w1.w};
  unsigned short ru[8];
  #pragma unroll
  for (int j = 0; j < 8; ++j) {
    float gf = bf2f(gu[j]);
    float si = gf / (1.f + __expf(-gf));
    ru[j] = f2bf(f[j] * rms * wv[j] * si);
  }
  *(uint4*)(o + base) = *(uint4*)ru;
}

// ================= launch =================
extern "C" void kernel_launch(void* const* d_in, const int* in_sizes, int n_in,
                              void* d_out, int out_size, void* d_ws, size_t ws_size,
                              hipStream_t stream) {
  (void)in_sizes; (void)n_in; (void)out_size; (void)ws_size;
  const float* x   = (const float*)d_in[0];
  const float* Wq  = (const float*)d_in[1];
  const float* Wk  = (const float*)d_in[2];
  const float* Wv  = (const float*)d_in[3];
  const float* Wg  = (const float*)d_in[4];
  const float* Wgk = (const float*)d_in[5];
  const float* bgk = (const float*)d_in[6];
  const float* Wo  = (const float*)d_in[7];
  const float* nw  = (const float*)d_in[8];

  char* ws = (char*)d_ws;
  const size_t MB = 1024 * 1024;
  unsigned short* xb  = (unsigned short*)(ws + 0);        // 16MB
  unsigned short* wqT = (unsigned short*)(ws + 16*MB);    // 8MB
  unsigned short* wkT = (unsigned short*)(ws + 24*MB);    // 8MB
  unsigned short* wvT = (unsigned short*)(ws + 32*MB);    // 16MB
  unsigned short* wgT = (unsigned short*)(ws + 48*MB);    // 16MB
  unsigned short* woT = (unsigned short*)(ws + 64*MB);    // 16MB
  unsigned short* qb  = (unsigned short*)(ws + 80*MB);    // 16MB
  unsigned short* kb  = (unsigned short*)(ws + 96*MB);    // 16MB
  unsigned short* vb  = (unsigned short*)(ws + 112*MB);   // 32MB
  unsigned short* gb  = (unsigned short*)(ws + 144*MB);   // 32MB
  float* gkb          = (float*)(ws + 176*MB);            // 128KB
  // aliases (dead-after-use regions):
  unsigned short* ktg = wqT;   // 16MB over wqT+wkT (dead after k-GEMM)
  unsigned short* vtg = wvT;   // 32MB over wvT+wgT (dead after g-GEMM)
  unsigned short* oat = vb;    // 32MB over vb (dead after v-transpose)

  cast_f32_bf16<<<4096, 256, 0, stream>>>(x, xb, 4096 * 2048 / 8);
  transpose_cast<<<dim3(32, 32), 256, 0, stream>>>(Wq, wqT, 2048, 2048);
  transpose_cast<<<dim3(32, 32), 256, 0, stream>>>(Wk, wkT, 2048, 2048);
  transpose_cast<<<dim3(64, 32), 256, 0, stream>>>(Wv, wvT, 2048, 4096);
  transpose_cast<<<dim3(64, 32), 256, 0, stream>>>(Wg, wgT, 2048, 4096);
  transpose_cast<<<dim3(32, 64), 256, 0, stream>>>(Wo, woT, 4096, 2048);
  gk_proj<<<4096, 256, 0, stream>>>(x, Wgk, bgk, gkb);

  gemm_bt<1><<<dim3(16, 32), 256, 0, stream>>>(xb, wqT, qb, 4096, 2048, 2048);
  gemm_bt<1><<<dim3(16, 32), 256, 0, stream>>>(xb, wkT, kb, 4096, 2048, 2048);
  gemm_bt<1><<<dim3(32, 32), 256, 0, stream>>>(xb, wvT, vb, 4096, 4096, 2048);
  gemm_bt<1><<<dim3(32, 32), 256, 0, stream>>>(xb, wgT, gb, 4096, 4096, 2048);

  bt_transpose<<<dim3(32, 4, 16), 256, 0, stream>>>(kb, ktg, 2048, 256);  // k -> kT_g (over wqT/wkT)
  bt_transpose<<<dim3(32, 8, 16), 256, 0, stream>>>(vb, vtg, 4096, 512);  // v -> vT_g (over wvT/wgT)

  gla_kernel<<<128, 256, 0, stream>>>(qb, kb, ktg, vtg, gkb, oat);
  norm_gate<<<8192, 256, 0, stream>>>(oat, gb, nw);

  gemm_bt<0><<<dim3(16, 32), 256, 0, stream>>>(oat, woT, d_out, 4096, 2048, 4096);
}

// Round 8
// 666.880 us; speedup vs baseline: 3.8121x; 1.0900x over previous
//
#include <hip/hip_runtime.h>
#include <cstdint>
#include <cstddef>

// ---- problem constants ----
#define NB 2
#define TSEQ 2048
#define HIDD 2048
#define NH 8
#define DKD 256
#define DVD 512
#define CHK 64
#define NCH 32
#define HDKD 2048
#define HDVD 4096

typedef __attribute__((ext_vector_type(8))) short s16x8;  // 8 bf16 (4 VGPRs)
typedef __attribute__((ext_vector_type(4))) float fx4;    // MFMA accum

__device__ __forceinline__ float bf2f(unsigned short u) {
  union { float f; uint32_t i; } x; x.i = ((uint32_t)u) << 16; return x.f;
}
__device__ __forceinline__ unsigned short f2bf(float f) {
  union { float f; uint32_t i; } x; x.f = f;
  uint32_t r = (x.i + 0x7fffu + ((x.i >> 16) & 1u)) >> 16;
  return (unsigned short)r;
}

// async global->LDS, 16B per lane; LDS dest = wave-uniform base + lane*16
__device__ __forceinline__ void gload16(const unsigned short* g, unsigned short* l) {
  __builtin_amdgcn_global_load_lds(
      (const __attribute__((address_space(1))) void*)g,
      (__attribute__((address_space(3))) void*)l, 16, 0, 0);
}

// ================= elementwise f32 -> bf16 cast =================
__global__ __launch_bounds__(256) void cast_f32_bf16(const float* __restrict__ in,
                                                     unsigned short* __restrict__ out, int n8) {
  int idx = blockIdx.x * 256 + threadIdx.x;
  if (idx >= n8) return;
  const float4* p = (const float4*)(in + (size_t)idx * 8);
  float4 a = p[0], b = p[1];
  unsigned short u[8];
  u[0]=f2bf(a.x); u[1]=f2bf(a.y); u[2]=f2bf(a.z); u[3]=f2bf(a.w);
  u[4]=f2bf(b.x); u[5]=f2bf(b.y); u[6]=f2bf(b.z); u[7]=f2bf(b.w);
  *(uint4*)(out + (size_t)idx * 8) = *(uint4*)u;
}

// ================= transpose + cast: in[R][C] f32 -> out[C][R] bf16 =================
__global__ __launch_bounds__(256) void transpose_cast(const float* __restrict__ in,
                                                      unsigned short* __restrict__ out,
                                                      int R, int C) {
  __shared__ float tile[64][65];
  const int tid = threadIdx.x;
  const int c0 = blockIdx.x * 64, r0 = blockIdx.y * 64;
  #pragma unroll
  for (int it = 0; it < 4; ++it) {
    int idx = tid + it * 256;
    int row = idx >> 4, c4 = (idx & 15) * 4;
    float4 v = *(const float4*)(in + (size_t)(r0 + row) * C + c0 + c4);
    tile[row][c4 + 0] = v.x; tile[row][c4 + 1] = v.y;
    tile[row][c4 + 2] = v.z; tile[row][c4 + 3] = v.w;
  }
  __syncthreads();
  #pragma unroll
  for (int it = 0; it < 4; ++it) {
    int idx = tid + it * 256;
    int orow = idx >> 4, r4 = (idx & 15) * 4;
    ushort4 u;
    u.x = f2bf(tile[r4 + 0][orow]);
    u.y = f2bf(tile[r4 + 1][orow]);
    u.z = f2bf(tile[r4 + 2][orow]);
    u.w = f2bf(tile[r4 + 3][orow]);
    *(ushort4*)(out + (size_t)(c0 + orow) * R + r0 + r4) = u;
  }
}

// ================= bf16 transpose per (b,h): in[b*T + t][h*DF + d] -> out[(b*H+h)*DF + d][t] =================
__global__ __launch_bounds__(256) void bt_transpose(const unsigned short* __restrict__ in,
                                                    unsigned short* __restrict__ out,
                                                    int inW, int DF) {
  __shared__ unsigned short tile[64][65];
  const int tid = threadIdx.x;
  const int t0 = blockIdx.x * 64, c0 = blockIdx.y * 64;
  const int b = blockIdx.z >> 3, h = blockIdx.z & 7;
  #pragma unroll
  for (int it = 0; it < 2; ++it) {
    int idx = tid + it * 256;
    int tr = idx >> 3, tc0 = (idx & 7) * 8;
    uint4 v = *(const uint4*)(in + (size_t)(b * 2048 + t0 + tr) * inW + h * DF + c0 + tc0);
    const unsigned short* u = (const unsigned short*)&v;
    #pragma unroll
    for (int j = 0; j < 8; ++j) tile[tr][tc0 + j] = u[j];
  }
  __syncthreads();
  #pragma unroll
  for (int it = 0; it < 2; ++it) {
    int idx = tid + it * 256;
    int od = idx >> 3, ot0 = (idx & 7) * 8;
    unsigned short u[8];
    #pragma unroll
    for (int j = 0; j < 8; ++j) u[j] = tile[ot0 + j][od];
    *(uint4*)(out + ((size_t)blockIdx.z * DF + c0 + od) * 2048 + t0 + ot0) = *(uint4*)u;
  }
}

// ================= gk projection: log_sigmoid(x @ Wgk + bgk)/16, all fp32 =================
__global__ __launch_bounds__(256) void gk_proj(const float* __restrict__ x,
                                               const float* __restrict__ Wgk,
                                               const float* __restrict__ bgk,
                                               float* __restrict__ gk) {
  const int row = blockIdx.x, tid = threadIdx.x;
  const float* xr = x + (size_t)row * HIDD;
  float acc[8];
  #pragma unroll
  for (int h = 0; h < 8; ++h) acc[h] = 0.f;
  for (int i = tid; i < HIDD; i += 256) {
    float xv = xr[i];
    const float4* wr = (const float4*)(Wgk + (size_t)i * 8);
    float4 w0 = wr[0], w1 = wr[1];
    acc[0] += xv * w0.x; acc[1] += xv * w0.y; acc[2] += xv * w0.z; acc[3] += xv * w0.w;
    acc[4] += xv * w1.x; acc[5] += xv * w1.y; acc[6] += xv * w1.z; acc[7] += xv * w1.w;
  }
  #pragma unroll
  for (int off = 32; off; off >>= 1) {
    #pragma unroll
    for (int h = 0; h < 8; ++h) acc[h] += __shfl_xor(acc[h], off, 64);
  }
  __shared__ float red[4][8];
  if ((tid & 63) == 0) {
    #pragma unroll
    for (int h = 0; h < 8; ++h) red[tid >> 6][h] = acc[h];
  }
  __syncthreads();
  if (tid < 8) {
    float z = red[0][tid] + red[1][tid] + red[2][tid] + red[3][tid] + bgk[tid];
    float ls = fminf(z, 0.f) - log1pf(__expf(-fabsf(z)));
    gk[(size_t)row * 8 + tid] = ls * (1.0f / 16.0f);
  }
}

// ================= bf16 GEMM (dbuf 2-phase): C[M][N] = A[M][K] * BT[N][K]^T =================
// 128x128 tile, BK=64, global_load_lds w16 source-swizzled, LDS double-buffer,
// stage(kt+1) issued BEFORE compute(kt), ONE barrier per K-step (T3 minimum-2-phase).
template<int OUT_BF16>
__global__ __launch_bounds__(256, 2) void gemm_bt(const unsigned short* __restrict__ A,
                                                  const unsigned short* __restrict__ BT,
                                                  void* __restrict__ C,
                                                  int M, int N, int K) {
  __shared__ unsigned short smem[2][16384];  // per buf: As [0,8192), Bs [8192,16384)
  const int tid = threadIdx.x, l = tid & 63;
  const int l15 = l & 15, l4 = l >> 4;
  const int w = tid >> 6, wm = w >> 1, wn = w & 1;
  const int m0 = blockIdx.y * 128, n0 = blockIdx.x * 128;
  const int nk = K >> 6;

  fx4 zero = {0.f, 0.f, 0.f, 0.f};
  fx4 acc[4][4];
  #pragma unroll
  for (int mi = 0; mi < 4; ++mi)
    #pragma unroll
    for (int ni = 0; ni < 4; ++ni) acc[mi][ni] = zero;

  // per-lane staging geometry: chunk = (w*4+i)*64 + l; row = chunk>>3; swizzled source octet
  const int srow[4] = { (w*4+0)*8 + (l>>3), (w*4+1)*8 + (l>>3), (w*4+2)*8 + (l>>3), (w*4+3)*8 + (l>>3) };
  const int soct[4] = { (l&7) ^ (srow[0]&7), (l&7) ^ (srow[1]&7), (l&7) ^ (srow[2]&7), (l&7) ^ (srow[3]&7) };

  auto stage = [&](int kt, int buf) {
    #pragma unroll
    for (int i = 0; i < 4; ++i) {
      gload16(A  + (size_t)(m0 + srow[i]) * K + kt * 64 + soct[i] * 8, smem[buf] + (w*4+i)*512);
      gload16(BT + (size_t)(n0 + srow[i]) * K + kt * 64 + soct[i] * 8, smem[buf] + 8192 + (w*4+i)*512);
    }
  };

  stage(0, 0);
  __syncthreads();  // drains prologue stage
  for (int kt = 0; kt < nk; ++kt) {
    const int cur = kt & 1;
    if (kt + 1 < nk) stage(kt + 1, cur ^ 1);  // async; overlaps MFMA below
    const unsigned short* As = smem[cur];
    const unsigned short* Bs = smem[cur] + 8192;
    #pragma unroll
    for (int ks = 0; ks < 2; ++ks) {
      s16x8 af[4], bf[4];
      #pragma unroll
      for (int i = 0; i < 4; ++i) {
        int arow = wm * 64 + i * 16 + l15;
        af[i] = *(const s16x8*)(As + arow * 64 + (((ks*4 + l4) ^ (arow & 7)) << 3));
        int brow = wn * 64 + i * 16 + l15;
        bf[i] = *(const s16x8*)(Bs + brow * 64 + (((ks*4 + l4) ^ (brow & 7)) << 3));
      }
      #pragma unroll
      for (int mi = 0; mi < 4; ++mi)
        #pragma unroll
        for (int ni = 0; ni < 4; ++ni)
          acc[mi][ni] = __builtin_amdgcn_mfma_f32_16x16x32_bf16(af[mi], bf[ni], acc[mi][ni], 0, 0, 0);
    }
    __syncthreads();  // reads of cur done + stage into cur^1 landed
  }

  if (OUT_BF16) {
    // LDS-bounce epilogue in smem[0]: [128][128] bf16 swizzled, coalesced b128 stores
    unsigned short* cs = smem[0];
    #pragma unroll
    for (int mi = 0; mi < 4; ++mi)
      #pragma unroll
      for (int r = 0; r < 4; ++r) {
        int row = wm * 64 + mi * 16 + l4 * 4 + r;
        #pragma unroll
        for (int ni = 0; ni < 4; ++ni) {
          int col = wn * 64 + ni * 16 + l15;
          cs[row * 128 + (((col >> 3) ^ (row & 7)) << 3) + (col & 7)] = f2bf(acc[mi][ni][r]);
        }
      }
    __syncthreads();
    #pragma unroll
    for (int it = 0; it < 8; ++it) {
      int idx = tid + it * 256;
      int row = idx >> 4, cl = idx & 15;
      uint4 vv = *(const uint4*)(cs + row * 128 + ((cl ^ (row & 7)) << 3));
      *(uint4*)((unsigned short*)C + (size_t)(m0 + row) * N + n0 + cl * 8) = vv;
    }
  } else {
    #pragma unroll
    for (int mi = 0; mi < 4; ++mi)
      #pragma unroll
      for (int r = 0; r < 4; ++r) {
        const size_t row = m0 + wm * 64 + mi * 16 + l4 * 4 + r;
        #pragma unroll
        for (int ni = 0; ni < 4; ++ni) {
          const int col = n0 + wn * 64 + ni * 16 + l15;
          ((float*)C)[row * N + col] = acc[mi][ni][r];
        }
      }
  }
}

// ================= chunked GLA scan (v4: 256 blocks x 8 waves, 3x shorter wave chain) =================
// grid = B*H*(DV/32) = 256 blocks, 512 threads. bh = blk&15 -> 16 dv-siblings share blk%8 (XCD L2).
// Wave (wr,wc): wr=w>>1 owns q-row tile i=wr*16..+16; wc=w&1 owns dv slice wc*16 of the block's 32.
// S[256dk][32dv] fp32: wave owns dk slice wr*64 x dv 16 -> 4 frags/lane.
// LDS 112.8KB: skbuf 32K (ST[32][256] P0-1 / kT[256][64] P2-3), qs 32K, kst 32K, vTs 2x4K, Als 8K.
// q/k/vT(c+1) staged at P3(c) under S-update MFMAs; kT(c) staged at P2 under A@v.
__global__ __launch_bounds__(512, 1) void gla_kernel(const unsigned short* __restrict__ qb,
                                                     const unsigned short* __restrict__ kb,
                                                     const unsigned short* __restrict__ ktg,
                                                     const unsigned short* __restrict__ vtg,
                                                     const float* __restrict__ gkw,
                                                     unsigned short* __restrict__ oat) {
  const int blk = blockIdx.x;
  const int bh = blk & 15, dvb = blk >> 4;
  const int b = bh >> 3, h = bh & 7;
  const int dv0 = dvb * 32;
  const int tid = threadIdx.x, l = tid & 63, w = tid >> 6;
  const int wr = w >> 1, wc = w & 1;
  const int l15 = l & 15, l4 = l >> 4;

  __shared__ __align__(16) unsigned short skbuf[16384];  // 32KB: ST[32][256] / kT[256][64]
  __shared__ __align__(16) unsigned short qs[16384];     // 32KB: q [64][256] swz
  __shared__ __align__(16) unsigned short kst[16384];    // 32KB: k [64][256] swz
  __shared__ __align__(16) unsigned short vTs[2][2048];  // 2x4KB: vT [32][64] swz dbuf
  __shared__ __align__(16) unsigned short Als[4096];     // 8KB: A [64][64] swz
  __shared__ float gis[64], els[64], eis[64];

  fx4 zero = {0.f, 0.f, 0.f, 0.f};
  fx4 S[4];
  #pragma unroll
  for (int t = 0; t < 4; ++t) S[t] = zero;

  const unsigned short* qbase = qb + (size_t)b * TSEQ * HDKD + h * DKD;
  const unsigned short* kbase = kb + (size_t)b * TSEQ * HDKD + h * DKD;
  const unsigned short* ktg_bh = ktg + (size_t)(b * 8 + h) * DKD * TSEQ;
  const unsigned short* vtg_bh = vtg + ((size_t)(b * 8 + h) * DVD + dv0) * TSEQ;
  const float*  gbase = gkw + (size_t)b * TSEQ * NH + h;
  unsigned short* obase = oat + (size_t)b * TSEQ * HDVD + h * DVD + dv0;

  const int dvl = wc * 16 + l15;      // block-local dv 0..31 (B-operand col)
  const int irow = wr * 16 + l15;     // A-operand row for q / Als

  // ---- staging (per-wave slices; LDS linear dest, source-side XOR swizzle) ----
  auto stage_qk = [&](int t0) {
    #pragma unroll
    for (int i = 0; i < 4; ++i) {
      int s = (w * 4 + i) * 64 + l;          // 0..2047; row 0..63, 32 octets/row
      int row = s >> 5, o = s & 31;
      int osw = o ^ (row & 7);
      gload16(qbase + (size_t)(t0 + row) * HDKD + (osw << 3), qs  + (w * 4 + i) * 512);
      gload16(kbase + (size_t)(t0 + row) * HDKD + (osw << 3), kst + (w * 4 + i) * 512);
    }
  };
  auto stage_v = [&](int t0, int buf) {
    if (w < 4) {
      int s = w * 64 + l;                    // 0..255; dv row 0..31, 8 octets/row
      int dv = s >> 3, os = s & 7;
      gload16(vtg_bh + (size_t)dv * TSEQ + t0 + ((os ^ (dv & 7)) << 3), vTs[buf] + w * 512);
    }
  };

  // prologue: stage chunk 0 (drained at P0(0)-end barrier)
  stage_qk(0);
  stage_v(0, 0);

  for (int c = 0; c < NCH; ++c) {
    const int t0 = c * CHK;

    // ---- P0: wave0 cumsum -> gis/els/eis; ST(bf16) <- S accumulators ----
    if (tid < 64) {
      float xg = gbase[(size_t)(t0 + tid) * NH];
      #pragma unroll
      for (int off = 1; off < 64; off <<= 1) {
        float y = __shfl_up(xg, off, 64);
        if (l >= off) xg += y;
      }
      gis[tid] = xg;
      float gl = __shfl(xg, 63, 64);
      els[tid] = __expf(gl - xg);
      eis[tid] = 0.0625f * __expf(xg);
    }
    #pragma unroll
    for (int t = 0; t < 4; ++t) {
      const int dk0 = wr * 64 + t * 16 + l4 * 4;
      ushort4 p;
      p.x = f2bf(S[t].x); p.y = f2bf(S[t].y); p.z = f2bf(S[t].z); p.w = f2bf(S[t].w);
      *(ushort4*)(skbuf + dvl * 256 + (((dk0 >> 3) ^ (dvl & 7)) << 3) + (dk0 & 7)) = p;
    }
    __syncthreads();

    // ---- P1: o1 = q @ S^T-frags (1 tile);  ar[jt] = q @ k^T (2 j-tiles) ----
    fx4 o1 = zero, ar[2] = {zero, zero};
    #pragma unroll
    for (int ks = 0; ks < 8; ++ks) {
      s16x8 qf = *(const s16x8*)(qs + irow * 256 + (((ks * 4 + l4) ^ (irow & 7)) << 3));
      s16x8 stf = *(const s16x8*)(skbuf + dvl * 256 + (((ks * 4 + l4) ^ (dvl & 7)) << 3));
      o1 = __builtin_amdgcn_mfma_f32_16x16x32_bf16(qf, stf, o1, 0, 0, 0);
      #pragma unroll
      for (int jt = 0; jt < 2; ++jt) {
        const int krow = wc * 32 + jt * 16 + l15;
        s16x8 kf = *(const s16x8*)(kst + krow * 256 + (((ks * 4 + l4) ^ (krow & 7)) << 3));
        ar[jt] = __builtin_amdgcn_mfma_f32_16x16x32_bf16(qf, kf, ar[jt], 0, 0, 0);
      }
    }
    #pragma unroll
    for (int jt = 0; jt < 2; ++jt) {
      const int j = wc * 32 + jt * 16 + l15;
      const float gj = gis[j];
      #pragma unroll
      for (int r = 0; r < 4; ++r) {
        const int i = wr * 16 + l4 * 4 + r;
        float av = (i >= j) ? ar[jt][r] * 0.0625f * __expf(gis[i] - gj) : 0.f;
        Als[i * 64 + (((j >> 3) ^ (i & 7)) << 3) + (j & 7)] = f2bf(av);
      }
    }
    #pragma unroll
    for (int r = 0; r < 4; ++r) o1[r] *= eis[wr * 16 + l4 * 4 + r];
    __syncthreads();

    // ---- P2: issue kT stage into skbuf; o = o1 + A @ vT-frags; store o ----
    #pragma unroll
    for (int i = 0; i < 4; ++i) {
      int s = (w * 4 + i) * 64 + l;          // 0..2047; dk 0..255, 8 octets/row
      int dk = s >> 3, os = s & 7;
      gload16(ktg_bh + (size_t)dk * TSEQ + t0 + ((os ^ (dk & 7)) << 3), skbuf + (w * 4 + i) * 512);
    }
    s16x8 vf[2], vf2[2];
    #pragma unroll
    for (int ks = 0; ks < 2; ++ks)
      vf[ks] = *(const s16x8*)(vTs[c & 1] + dvl * 64 + (((ks * 4 + l4) ^ (dvl & 7)) << 3));
    #pragma unroll
    for (int ks = 0; ks < 2; ++ks)
      #pragma unroll
      for (int j = 0; j < 8; ++j) {
        float e = els[ks * 32 + l4 * 8 + j];
        vf2[ks][j] = (short)f2bf(bf2f((unsigned short)vf[ks][j]) * e);
      }
    #pragma unroll
    for (int ks = 0; ks < 2; ++ks) {
      s16x8 af = *(const s16x8*)(Als + irow * 64 + (((ks * 4 + l4) ^ (irow & 7)) << 3));
      o1 = __builtin_amdgcn_mfma_f32_16x16x32_bf16(af, vf[ks], o1, 0, 0, 0);
    }
    #pragma unroll
    for (int r = 0; r < 4; ++r) {
      const int tt = t0 + wr * 16 + l4 * 4 + r;
      obase[(size_t)tt * HDVD + dvl] = f2bf(o1[r]);
    }
    __syncthreads();  // drains kT gloads

    // ---- P3: issue q/k/vT stages for c+1 (hidden under MFMAs); S = exp(gl)*S + kT' @ v ----
    {
      const int cn = (c + 1 < NCH) ? c + 1 : c;   // last iter re-stages (harmless, never read)
      stage_qk(cn * CHK);
      stage_v(cn * CHK, (c + 1) & 1);
    }
    {
      const float egl = __expf(gis[63]);
      #pragma unroll
      for (int t = 0; t < 4; ++t) {
        S[t].x *= egl; S[t].y *= egl; S[t].z *= egl; S[t].w *= egl;
        const int dk = wr * 64 + t * 16 + l15;
        #pragma unroll
        for (int ks = 0; ks < 2; ++ks) {
          s16x8 ktf = *(const s16x8*)(skbuf + dk * 64 + (((ks * 4 + l4) ^ (dk & 7)) << 3));
          S[t] = __builtin_amdgcn_mfma_f32_16x16x32_bf16(ktf, vf2[ks], S[t], 0, 0, 0);
        }
      }
    }
    __syncthreads();  // drains next-chunk stages; protects skbuf before P0(c+1)
  }
}

// ================= fused RMSnorm * norm_w * silu(g), in-place on o =================
__global__ __launch_bounds__(256) void norm_gate(unsigned short* __restrict__ o,
                                                 const unsigned short* __restrict__ g,
                                                 const float* __restrict__ nw) {
  const int seg = blockIdx.x * 4 + (threadIdx.x >> 6);
  const int l = threadIdx.x & 63;
  const size_t base = (size_t)seg * 512 + l * 8;
  uint4 ov = *(const uint4*)(o + base);
  const unsigned short* ou = (const unsigned short*)&ov;
  float f[8], ss = 0.f;
  #pragma unroll
  for (int j = 0; j < 8; ++j) { f[j] = bf2f(ou[j]); ss += f[j] * f[j]; }
  #pragma unroll
  for (int off = 32; off; off >>= 1) ss += __shfl_xor(ss, off, 64);
  const float rms = rsqrtf(ss * (1.0f / 512.0f) + 1e-5f);
  uint4 gv = *(const uint4*)(g + base);
  const unsigned short* gu = (const unsigned short*)&gv;
  const float4 w0 = *(const float4*)(nw + l * 8);
  const float4 w1 = *(const float4*)(nw + l * 8 + 4);
  float wv[8] = {w0.x, w0.y, w0.z, w0.w, w1.x, w1.y, w1.z, w1.w};
  unsigned short ru[8];
  #pragma unroll
  for (int j = 0; j < 8; ++j) {
    float gf = bf2f(gu[j]);
    float si = gf / (1.f + __expf(-gf));
    ru[j] = f2bf(f[j] * rms * wv[j] * si);
  }
  *(uint4*)(o + base) = *(uint4*)ru;
}

// ================= launch =================
extern "C" void kernel_launch(void* const* d_in, const int* in_sizes, int n_in,
                              void* d_out, int out_size, void* d_ws, size_t ws_size,
                              hipStream_t stream) {
  (void)in_sizes; (void)n_in; (void)out_size; (void)ws_size;
  const float* x   = (const float*)d_in[0];
  const float* Wq  = (const float*)d_in[1];
  const float* Wk  = (const float*)d_in[2];
  const float* Wv  = (const float*)d_in[3];
  const float* Wg  = (const float*)d_in[4];
  const float* Wgk = (const float*)d_in[5];
  const float* bgk = (const float*)d_in[6];
  const float* Wo  = (const float*)d_in[7];
  const float* nw  = (const float*)d_in[8];

  char* ws = (char*)d_ws;
  const size_t MB = 1024 * 1024;
  unsigned short* xb  = (unsigned short*)(ws + 0);        // 16MB
  unsigned short* wqT = (unsigned short*)(ws + 16*MB);    // 8MB
  unsigned short* wkT = (unsigned short*)(ws + 24*MB);    // 8MB
  unsigned short* wvT = (unsigned short*)(ws + 32*MB);    // 16MB
  unsigned short* wgT = (unsigned short*)(ws + 48*MB);    // 16MB
  unsigned short* woT = (unsigned short*)(ws + 64*MB);    // 16MB
  unsigned short* qb  = (unsigned short*)(ws + 80*MB);    // 16MB
  unsigned short* kb  = (unsigned short*)(ws + 96*MB);    // 16MB
  unsigned short* vb  = (unsigned short*)(ws + 112*MB);   // 32MB
  unsigned short* gb  = (unsigned short*)(ws + 144*MB);   // 32MB
  float* gkb          = (float*)(ws + 176*MB);            // 128KB
  // aliases (dead-after-use regions):
  unsigned short* ktg = wqT;   // 16MB over wqT+wkT (dead after k-GEMM)
  unsigned short* vtg = wvT;   // 32MB over wvT+wgT (dead after g-GEMM)
  unsigned short* oat = vb;    // 32MB over vb (dead after v-transpose)

  cast_f32_bf16<<<4096, 256, 0, stream>>>(x, xb, 4096 * 2048 / 8);
  transpose_cast<<<dim3(32, 32), 256, 0, stream>>>(Wq, wqT, 2048, 2048);
  transpose_cast<<<dim3(32, 32), 256, 0, stream>>>(Wk, wkT, 2048, 2048);
  transpose_cast<<<dim3(64, 32), 256, 0, stream>>>(Wv, wvT, 2048, 4096);
  transpose_cast<<<dim3(64, 32), 256, 0, stream>>>(Wg, wgT, 2048, 4096);
  transpose_cast<<<dim3(32, 64), 256, 0, stream>>>(Wo, woT, 4096, 2048);
  gk_proj<<<4096, 256, 0, stream>>>(x, Wgk, bgk, gkb);

  gemm_bt<1><<<dim3(16, 32), 256, 0, stream>>>(xb, wqT, qb, 4096, 2048, 2048);
  gemm_bt<1><<<dim3(16, 32), 256, 0, stream>>>(xb, wkT, kb, 4096, 2048, 2048);
  gemm_bt<1><<<dim3(32, 32), 256, 0, stream>>>(xb, wvT, vb, 4096, 4096, 2048);
  gemm_bt<1><<<dim3(32, 32), 256, 0, stream>>>(xb, wgT, gb, 4096, 4096, 2048);

  bt_transpose<<<dim3(32, 4, 16), 256, 0, stream>>>(kb, ktg, 2048, 256);  // k -> kT_g (over wqT/wkT)
  bt_transpose<<<dim3(32, 8, 16), 256, 0, stream>>>(vb, vtg, 4096, 512);  // v -> vT_g (over wvT/wgT)

  gla_kernel<<<256, 512, 0, stream>>>(qb, kb, ktg, vtg, gkb, oat);
  norm_gate<<<8192, 256, 0, stream>>>(oat, gb, nw);

  gemm_bt<0><<<dim3(16, 32), 256, 0, stream>>>(oat, woT, d_out, 4096, 2048, 4096);
}